// Round 13
// baseline (1638.968 us; speedup 1.0000x reference)
//
#include <hip/hip_runtime.h>
#include <hip/hip_bf16.h>

typedef unsigned short u16;
typedef unsigned int   u32;
typedef __attribute__((ext_vector_type(8))) __bf16 bf16x8;
typedef __attribute__((ext_vector_type(4))) float  f32x4;
typedef __attribute__((ext_vector_type(8))) unsigned short u16x8;

static constexpr int NB  = 8;      // batch
static constexpr int TT  = 511;    // seq len
static constexpr int CC  = 1024;   // model dim
static constexpr int HH  = 16;     // heads
static constexpr int LL  = 8;      // layers
static constexpr int VV  = 128;    // vocab
static constexpr int FF_ = 4096;   // ffn dim
static constexpr int MV  = NB * TT;   // 4088 valid rows
static constexpr int MP  = 4096;      // padded rows
static constexpr int TP  = 512;       // padded seq for vt
static constexpr size_t PH  = (size_t)MP * VV;   // head partial slice stride
static constexpr size_t PB2 = (size_t)MP * CC;   // mlp2 partial slice stride

#define DEVI static __device__ __forceinline__

DEVI u16 f2bf(float f) {
  u32 u = __builtin_bit_cast(u32, f);
  u = (u + 0x7fffu + ((u >> 16) & 1u)) >> 16;
  return (u16)u;
}

DEVI void gload16(const void* g, void* lds) {
  auto gp = (const __attribute__((address_space(1))) u32*)(uintptr_t)g;
  auto lp = (__attribute__((address_space(3))) u32*)(uintptr_t)lds;
  __builtin_amdgcn_global_load_lds(gp, lp, 16, 0, 0);
}

// ---- conflict-free 64x64 transpose tile: in [K][N] f32 (at kb,nb) -> out [N][K] bf16 ----
// tile[n][kc] dwords (kc = k/2, row stride 33 dwords): write banks (n+kc)%32 spread 2-way;
// read 4 dwords/row also 2-way. Output is 16B u16x8 store.
DEVI void trans_tile(u32* tile, const float* __restrict__ in, int N,
                     u16* __restrict__ out, int K, int t) {
  int c4 = (t & 15) * 4;
  int rp = t >> 4;
#pragma unroll
  for (int i = 0; i < 2; ++i) {
    int k = (rp + i * 16) * 2;
    float4 a = *(const float4*)(in + (size_t)k * N + c4);
    float4 b = *(const float4*)(in + (size_t)(k + 1) * N + c4);
    int kc = k >> 1;
    tile[(c4 + 0) * 33 + kc] = (u32)f2bf(a.x) | ((u32)f2bf(b.x) << 16);
    tile[(c4 + 1) * 33 + kc] = (u32)f2bf(a.y) | ((u32)f2bf(b.y) << 16);
    tile[(c4 + 2) * 33 + kc] = (u32)f2bf(a.z) | ((u32)f2bf(b.z) << 16);
    tile[(c4 + 3) * 33 + kc] = (u32)f2bf(a.w) | ((u32)f2bf(b.w) << 16);
  }
  __syncthreads();
  int k8 = (t & 7) * 8;
  int kc4 = k8 >> 1;
#pragma unroll
  for (int i = 0; i < 2; ++i) {
    int n = (t >> 3) + i * 32;
    u32 d[4];
#pragma unroll
    for (int c = 0; c < 4; ++c) d[c] = tile[n * 33 + kc4 + c];
    u16x8 o;
#pragma unroll
    for (int c = 0; c < 4; ++c) { o[2 * c] = (u16)d[c]; o[2 * c + 1] = (u16)(d[c] >> 16); }
    *(u16x8*)(out + (size_t)n * K + k8) = o;
  }
}

// ---------------- mega prologue: embed + all weight transposes + head cast + bias pack ----
// block ranges: [0,MP) embed ; [MP, MP+8192) QKV/Wp tiles ; +8192 W1 ; +8192 W2 ; rest prep
__global__ __launch_bounds__(256) void k_prep_all(const int* __restrict__ idx,
                                                  const float* __restrict__ tok,
                                                  const float* __restrict__ pos,
                                                  float* __restrict__ x,
                                                  const float* __restrict__ Wq,
                                                  const float* __restrict__ Wk,
                                                  const float* __restrict__ Wv,
                                                  const float* __restrict__ Wp,
                                                  const float* __restrict__ W1,
                                                  const float* __restrict__ W2,
                                                  const float* __restrict__ headw,
                                                  const float* __restrict__ bq,
                                                  const float* __restrict__ bk,
                                                  const float* __restrict__ bv,
                                                  u16* __restrict__ wqkv_t,
                                                  u16* __restrict__ wp_t,
                                                  u16* __restrict__ w1_t,
                                                  u16* __restrict__ w2_t,
                                                  u16* __restrict__ headb,
                                                  float* __restrict__ bqkv) {
  __shared__ u32 tile[64 * 33];
  int bid = blockIdx.x, t = threadIdx.x;
  if (bid < MP) {                      // ---- embedding ----
    int row = bid;
    int c4 = t * 4;
    if (row >= MV) {
      *(float4*)(x + (size_t)row * CC + c4) = make_float4(0.f, 0.f, 0.f, 0.f);
      return;
    }
    int tt = row % TT;
    int tid = idx[row];
    float4 a = *(const float4*)(tok + (size_t)tid * CC + c4);
    float4 p = *(const float4*)(pos + (size_t)tt * CC + c4);
    a.x += p.x; a.y += p.y; a.z += p.z; a.w += p.w;
    *(float4*)(x + (size_t)row * CC + c4) = a;
    return;
  }
  bid -= MP;
  if (bid < 8192) {                    // ---- Wq/Wk/Wv/Wp (CCxCC) ----
    int which = bid >> 11, rem = bid & 2047;
    int lyr = rem >> 8, ti = rem & 255;
    int nb = (ti & 15) * 64, kb = (ti >> 4) * 64;
    const float* in; u16* out;
    size_t sq = (size_t)CC * CC;
    if (which == 0)      { in = Wq + lyr * sq; out = wqkv_t + lyr * 3 * sq; }
    else if (which == 1) { in = Wk + lyr * sq; out = wqkv_t + lyr * 3 * sq + sq; }
    else if (which == 2) { in = Wv + lyr * sq; out = wqkv_t + lyr * 3 * sq + 2 * sq; }
    else                 { in = Wp + lyr * sq; out = wp_t + lyr * sq; }
    trans_tile(tile, in + (size_t)kb * CC + nb, CC, out + (size_t)nb * CC + kb, CC, t);
    return;
  }
  bid -= 8192;
  if (bid < 8192) {                    // ---- W1 [CC][FF] -> [FF][CC] ----
    int lyr = bid >> 10, ti = bid & 1023;
    int nb = (ti & 63) * 64, kb = (ti >> 6) * 64;
    trans_tile(tile, W1 + (size_t)lyr * CC * FF_ + (size_t)kb * FF_ + nb, FF_,
               w1_t + (size_t)lyr * FF_ * CC + (size_t)nb * CC + kb, CC, t);
    return;
  }
  bid -= 8192;
  if (bid < 8192) {                    // ---- W2 [FF][CC] -> [CC][FF] ----
    int lyr = bid >> 10, ti = bid & 1023;
    int nb = (ti & 15) * 64, kb = (ti >> 4) * 64;
    trans_tile(tile, W2 + (size_t)lyr * FF_ * CC + (size_t)kb * CC + nb, CC,
               w2_t + (size_t)lyr * CC * FF_ + (size_t)nb * FF_ + kb, FF_, t);
    return;
  }
  bid -= 8192;
  {                                    // ---- head cast + qkv bias pack ----
    int i = bid * 256 + t;
    if (i < VV * CC) {
      headb[i] = f2bf(headw[i]);
    } else {
      int j = i - VV * CC;
      if (j < LL * 3 * CC) {
        int l = j / (3 * CC), c = j % (3 * CC);
        float v = (c < CC) ? bq[l * CC + c] : (c < 2 * CC) ? bk[l * CC + c - CC] : bv[l * CC + c - 2 * CC];
        bqkv[j] = v;
      }
    }
  }
}

// ---------------- layernorm: f32 in -> bf16 out ----------------
__global__ __launch_bounds__(256) void k_ln(const float* __restrict__ x,
                                            const float* __restrict__ w,
                                            const float* __restrict__ b,
                                            u16* __restrict__ out) {
  int wid = threadIdx.x >> 6, l = threadIdx.x & 63;
  int row = blockIdx.x * 4 + wid;
  const float* xr = x + (size_t)row * CC;
  float4 v[4];
  float s = 0.f, sq = 0.f;
#pragma unroll
  for (int i = 0; i < 4; ++i) {
    v[i] = *(const float4*)(xr + (i * 64 + l) * 4);
    s  += v[i].x + v[i].y + v[i].z + v[i].w;
    sq += v[i].x * v[i].x + v[i].y * v[i].y + v[i].z * v[i].z + v[i].w * v[i].w;
  }
#pragma unroll
  for (int o = 32; o; o >>= 1) { s += __shfl_xor(s, o); sq += __shfl_xor(sq, o); }
  float mean = s * (1.f / CC);
  float var  = sq * (1.f / CC) - mean * mean;
  float rs = rsqrtf(var + 1e-5f);
#pragma unroll
  for (int i = 0; i < 4; ++i) {
    int c = (i * 64 + l) * 4;
    float4 wv = *(const float4*)(w + c);
    float4 bv = *(const float4*)(b + c);
    ushort4 o4;
    o4.x = f2bf((v[i].x - mean) * rs * wv.x + bv.x);
    o4.y = f2bf((v[i].y - mean) * rs * wv.y + bv.y);
    o4.z = f2bf((v[i].z - mean) * rs * wv.z + bv.z);
    o4.w = f2bf((v[i].w - mean) * rs * wv.w + bv.w);
    *(ushort4*)(out + (size_t)row * CC + c) = o4;
  }
}

// ---------------- fused: x += p0+p1+bias ; out = LN(x)*w + b ----------------
__global__ __launch_bounds__(256) void k_redln2(float* __restrict__ x,
                                                const float* __restrict__ pb,
                                                const float* __restrict__ bias,
                                                const float* __restrict__ w,
                                                const float* __restrict__ b,
                                                u16* __restrict__ out) {
  int wid = threadIdx.x >> 6, l = threadIdx.x & 63;
  int row = blockIdx.x * 4 + wid;
  float* xr = x + (size_t)row * CC;
  const float* pr = pb + (size_t)row * CC;
  float4 v[4];
  float s = 0.f, sq = 0.f;
#pragma unroll
  for (int i = 0; i < 4; ++i) {
    int c = (i * 64 + l) * 4;
    float4 xv = *(const float4*)(xr + c);
    float4 p0 = *(const float4*)(pr + c);
    float4 p1 = *(const float4*)(pr + PB2 + c);
    float4 bb = *(const float4*)(bias + c);
    v[i].x = xv.x + p0.x + p1.x + bb.x;
    v[i].y = xv.y + p0.y + p1.y + bb.y;
    v[i].z = xv.z + p0.z + p1.z + bb.z;
    v[i].w = xv.w + p0.w + p1.w + bb.w;
    *(float4*)(xr + c) = v[i];
    s  += v[i].x + v[i].y + v[i].z + v[i].w;
    sq += v[i].x * v[i].x + v[i].y * v[i].y + v[i].z * v[i].z + v[i].w * v[i].w;
  }
#pragma unroll
  for (int o = 32; o; o >>= 1) { s += __shfl_xor(s, o); sq += __shfl_xor(sq, o); }
  float mean = s * (1.f / CC);
  float var  = sq * (1.f / CC) - mean * mean;
  float rs = rsqrtf(var + 1e-5f);
#pragma unroll
  for (int i = 0; i < 4; ++i) {
    int c = (i * 64 + l) * 4;
    float4 wv = *(const float4*)(w + c);
    float4 bv = *(const float4*)(b + c);
    ushort4 o4;
    o4.x = f2bf((v[i].x - mean) * rs * wv.x + bv.x);
    o4.y = f2bf((v[i].y - mean) * rs * wv.y + bv.y);
    o4.z = f2bf((v[i].z - mean) * rs * wv.z + bv.z);
    o4.w = f2bf((v[i].w - mean) * rs * wv.w + bv.w);
    *(ushort4*)(out + (size_t)row * CC + c) = o4;
  }
}

// ---------------- 256x256 8-wave 8-PHASE pipelined GEMM (MLP1) ----------------
// EPI: 1 = bf16 out ; 2 = bf16 out + exact GELU
template <int EPI>
__global__ __launch_bounds__(512, 1) void k_gemm4(const u16* __restrict__ A,
                                                  const u16* __restrict__ Wt,
                                                  const float* __restrict__ bias,
                                                  u16* __restrict__ outb,
                                                  int N, int K, int gridN) {
  __shared__ char lds[2][4][16384];
  int t = threadIdx.x, l = t & 63, wid = t >> 6;
  int wr = wid >> 2, wc = wid & 3;     // 2 x 4 wave grid; wave C = 128(M) x 64(N)
  int lr = l & 15, lk16 = (l >> 4) * 16;

  // XCD-bijective block swizzle (m-major)
  int nwg = gridDim.x, wg = blockIdx.x;
  int qq = nwg >> 3, r8 = nwg & 7;
  int xcd = wg & 7, loc = wg >> 3;
  int swz = (xcd < r8 ? xcd * (qq + 1) : r8 * (qq + 1) + (xcd - r8) * qq) + loc;
  int mblk = swz / gridN, nblk = swz - mblk * gridN;
  int mb = mblk * 256, nb = nblk * 256;
  int NT = K >> 6;
  const u16* Ab = A  + (size_t)mb * K;
  const u16* Bb = Wt + (size_t)nb * K;

  int srow = t >> 3, skb = (t & 7) * 16;

  auto stageH = [&](int kt, int ht) {
    int b = kt & 1;
    const u16* src = (ht < 2) ? Ab : Bb;
    int rowbase = (ht & 1) << 7;
    char* dst = &lds[b][ht][0];
    const u16* s0 = src + (size_t)rowbase * K + kt * 64;
#pragma unroll
    for (int j = 0; j < 2; ++j) {
      int row = j * 64 + srow;
      int kb = skb ^ ((row & 7) << 4);
      gload16(s0 + (size_t)row * K + (kb >> 1), dst + j * 8192 + t * 16);
    }
  };

  f32x4 acc[8][4] = {};

  stageH(0, 0); stageH(0, 1); stageH(0, 2); stageH(0, 3);
  stageH(1, 2); stageH(1, 0); stageH(1, 3);
  asm volatile("s_waitcnt vmcnt(6)" ::: "memory");
  __builtin_amdgcn_s_barrier();
  __builtin_amdgcn_sched_barrier(0);

  for (int kt = 0; kt < NT; kt += 2) {
    bool s2 = (kt + 2) < NT, s3 = (kt + 3) < NT;
#pragma unroll
    for (int half = 0; half < 2; ++half) {
      int buf = half;
      bf16x8 Bf[2][4];
#pragma unroll
      for (int q = 0; q < 4; ++q) {
        bf16x8 Af[2][2];
        if (q == 0) {
#pragma unroll
          for (int ks = 0; ks < 2; ++ks)
#pragma unroll
            for (int nf = 0; nf < 4; ++nf) {
              int grow = ((wc & 1) << 6) + nf * 16 + lr;
              int kb = (ks * 64 + lk16) ^ ((grow & 7) << 4);
              Bf[ks][nf] = *(const bf16x8*)(&lds[buf][2 + (wc >> 1)][0] + grow * 128 + kb);
            }
        }
#pragma unroll
        for (int ks = 0; ks < 2; ++ks)
#pragma unroll
          for (int dm = 0; dm < 2; ++dm) {
            int mf = q * 2 + dm;
            int grow = wr * 64 + (mf & 3) * 16 + lr;
            int kb = (ks * 64 + lk16) ^ ((grow & 7) << 4);
            Af[ks][dm] = *(const bf16x8*)(&lds[buf][mf >> 2][0] + grow * 128 + kb);
          }
        if (half == 0) {
          if (q == 0)      stageH(kt + 1, 1);
          else if (q == 1) { if (s2) stageH(kt + 2, 2); }
          else if (q == 2) { if (s2) stageH(kt + 2, 0); }
          else             { if (s2) stageH(kt + 2, 3); }
        } else {
          if (q == 0)      { if (s2) stageH(kt + 2, 1); }
          else if (q == 1) { if (s3) stageH(kt + 3, 2); }
          else if (q == 2) { if (s3) stageH(kt + 3, 0); }
          else             { if (s3) stageH(kt + 3, 3); }
        }
        __builtin_amdgcn_sched_barrier(0);
        __builtin_amdgcn_s_barrier();
        asm volatile("s_waitcnt lgkmcnt(0)" ::: "memory");
        __builtin_amdgcn_sched_barrier(0);
        __builtin_amdgcn_s_setprio(1);
#pragma unroll
        for (int ks = 0; ks < 2; ++ks)
#pragma unroll
          for (int dm = 0; dm < 2; ++dm)
#pragma unroll
            for (int nf = 0; nf < 4; ++nf)
              acc[q * 2 + dm][nf] = __builtin_amdgcn_mfma_f32_16x16x32_bf16(
                  Af[ks][dm], Bf[ks][nf], acc[q * 2 + dm][nf], 0, 0, 0);
        __builtin_amdgcn_s_setprio(0);
        if (q == 3) {
          if (half == 0) {
            if (s2) asm volatile("s_waitcnt vmcnt(6)" ::: "memory");
            else    asm volatile("s_waitcnt vmcnt(0)" ::: "memory");
          } else if (s2) {
            if (s3) asm volatile("s_waitcnt vmcnt(6)" ::: "memory");
            else    asm volatile("s_waitcnt vmcnt(0)" ::: "memory");
          }
        }
        __builtin_amdgcn_sched_barrier(0);
        __builtin_amdgcn_s_barrier();
      }
    }
  }

  int r0 = (l >> 4) * 4;
#pragma unroll
  for (int mf = 0; mf < 8; ++mf) {
    int gr = mb + ((mf >> 2) << 7) + wr * 64 + (mf & 3) * 16 + r0;
#pragma unroll
    for (int nf = 0; nf < 4; ++nf) {
      int gc = nb + wc * 64 + nf * 16 + lr;
      float bv = bias[gc];
#pragma unroll
      for (int rr = 0; rr < 4; ++rr) {
        float v = acc[mf][nf][rr] + bv;
        size_t o = (size_t)(gr + rr) * N + gc;
        if constexpr (EPI == 1) {
          outb[o] = f2bf(v);
        } else {
          float g = 0.5f * v * (1.0f + erff(v * 0.70710678f));
          outb[o] = f2bf(g);
        }
      }
    }
  }
}

// ---------------- 256x192 8-wave 8-PHASE pipelined GEMM (QKV: full 256-block fill) ----------
template <int EPI>
__global__ __launch_bounds__(512, 1) void k_gemm5(const u16* __restrict__ A,
                                                  const u16* __restrict__ Wt,
                                                  const float* __restrict__ bias,
                                                  u16* __restrict__ outb,
                                                  int N, int K, int gridN) {
  __shared__ char lds[2][57344];
  int t = threadIdx.x, l = t & 63, wid = t >> 6;
  int wr = wid >> 2, wc = wid & 3;        // wave tile 128(M) x 48(N)
  int lr = l & 15, lk16 = (l >> 4) * 16;

  int nwg = gridDim.x, wg = blockIdx.x;
  int qq = nwg >> 3, r8 = nwg & 7;
  int xcd = wg & 7, loc = wg >> 3;
  int swz = (xcd < r8 ? xcd * (qq + 1) : r8 * (qq + 1) + (xcd - r8) * qq) + loc;
  int mblk = swz / gridN, nblk = swz - mblk * gridN;
  int mb = mblk * 256, nb = nblk * 192;
  int NT = K >> 6;
  const u16* Ab = A  + (size_t)mb * K;
  const u16* Bb = Wt + (size_t)nb * K;

  int srow = t >> 3, skb = (t & 7) * 16;

  auto stageA = [&](int kt, int ht) {
    int b = kt & 1;
    char* dst = &lds[b][ht * 16384];
    const u16* s0 = Ab + ((size_t)(ht << 7)) * K + kt * 64;
#pragma unroll
    for (int j = 0; j < 2; ++j) {
      int row = j * 64 + srow;
      int kb = skb ^ ((row & 7) << 4);
      gload16(s0 + (size_t)row * K + (kb >> 1), dst + j * 8192 + t * 16);
    }
  };
  auto stageB = [&](int kt, int bt) {
    int b = kt & 1;
    char* dst = &lds[b][32768 + bt * 8192];
    int row = bt * 64 + srow;
    int kb = skb ^ ((row & 7) << 4);
    gload16(Bb + (size_t)row * K + kt * 64 + (kb >> 1), dst + t * 16);
  };

  f32x4 acc[8][3] = {};

  stageA(0, 0); stageA(0, 1); stageB(0, 0); stageB(0, 1); stageB(0, 2);
  stageB(1, 0); stageB(1, 1); stageB(1, 2); stageA(1, 0);
  asm volatile("s_waitcnt vmcnt(5)" ::: "memory");
  __builtin_amdgcn_s_barrier();
  __builtin_amdgcn_sched_barrier(0);

  for (int kt = 0; kt < NT; kt += 2) {
    bool s2 = (kt + 2) < NT, s3 = (kt + 3) < NT;
#pragma unroll
    for (int half = 0; half < 2; ++half) {
      int buf = half;
      bf16x8 Bf[2][3];
#pragma unroll
      for (int q = 0; q < 4; ++q) {
        bf16x8 Af[2][2];
        if (q == 0) {
#pragma unroll
          for (int ks = 0; ks < 2; ++ks)
#pragma unroll
            for (int nf = 0; nf < 3; ++nf) {
              int grow = wc * 48 + nf * 16 + lr;
              int rr = grow & 63;
              int kb = (ks * 64 + lk16) ^ ((rr & 7) << 4);
              Bf[ks][nf] = *(const bf16x8*)(&lds[buf][32768 + (grow >> 6) * 8192] + rr * 128 + kb);
            }
        }
#pragma unroll
        for (int ks = 0; ks < 2; ++ks)
#pragma unroll
          for (int dm = 0; dm < 2; ++dm) {
            int mf = q * 2 + dm;
            int grow = wr * 64 + (mf & 3) * 16 + lr;
            int kb = (ks * 64 + lk16) ^ ((grow & 7) << 4);
            Af[ks][dm] = *(const bf16x8*)(&lds[buf][(mf >> 2) * 16384] + grow * 128 + kb);
          }
        if (half == 0) {
          if (q == 0)      stageA(kt + 1, 1);
          else if (q == 1) { if (s2) stageB(kt + 2, 0); }
          else if (q == 2) { if (s2) { stageB(kt + 2, 1); stageA(kt + 2, 0); } }
          else             { if (s2) stageB(kt + 2, 2); }
        } else {
          if (q == 0)      { if (s2) stageA(kt + 2, 1); }
          else if (q == 1) { if (s3) stageB(kt + 3, 0); }
          else if (q == 2) { if (s3) { stageB(kt + 3, 1); stageA(kt + 3, 0); } }
          else             { if (s3) stageB(kt + 3, 2); }
        }
        __builtin_amdgcn_sched_barrier(0);
        __builtin_amdgcn_s_barrier();
        asm volatile("s_waitcnt lgkmcnt(0)" ::: "memory");
        __builtin_amdgcn_sched_barrier(0);
        __builtin_amdgcn_s_setprio(1);
#pragma unroll
        for (int ks = 0; ks < 2; ++ks)
#pragma unroll
          for (int dm = 0; dm < 2; ++dm)
#pragma unroll
            for (int nf = 0; nf < 3; ++nf)
              acc[q * 2 + dm][nf] = __builtin_amdgcn_mfma_f32_16x16x32_bf16(
                  Af[ks][dm], Bf[ks][nf], acc[q * 2 + dm][nf], 0, 0, 0);
        __builtin_amdgcn_s_setprio(0);
        if (q == 3) {
          if (half == 0) {
            if (s2) asm volatile("s_waitcnt vmcnt(5)" ::: "memory");
            else    asm volatile("s_waitcnt vmcnt(0)" ::: "memory");
          } else if (s2) {
            if (s3) asm volatile("s_waitcnt vmcnt(5)" ::: "memory");
            else    asm volatile("s_waitcnt vmcnt(0)" ::: "memory");
          }
        }
        __builtin_amdgcn_sched_barrier(0);
        __builtin_amdgcn_s_barrier();
      }
    }
  }

  int r0 = (l >> 4) * 4;
#pragma unroll
  for (int mf = 0; mf < 8; ++mf) {
    int gr = mb + ((mf >> 2) << 7) + wr * 64 + (mf & 3) * 16 + r0;
#pragma unroll
    for (int nf = 0; nf < 3; ++nf) {
      int gc = nb + wc * 48 + nf * 16 + lr;
      float bv = bias[gc];
#pragma unroll
      for (int rr = 0; rr < 4; ++rr) {
        float v = acc[mf][nf][rr] + bv;
        size_t o = (size_t)(gr + rr) * N + gc;
        outb[o] = f2bf(v);
      }
    }
  }
}

// ---------------- 128x128 4-wave pipelined GEMM ----------------
// EPI: 0 = f32 resid-add store ; 3 = f32 row-guarded, no bias
template <int EPI>
__global__ __launch_bounds__(256, 2) void k_gemm3(const u16* __restrict__ A,
                                                  const u16* __restrict__ Wt,
                                                  const float* __restrict__ bias,
                                                  float* __restrict__ outf,
                                                  const float* __restrict__ resid,
                                                  int N, int K, int gridN, int Mv) {
  constexpr int BTILE = 16384;
  __shared__ u16 lds[2][128 * 64 * 2];

  int t = threadIdx.x, l = t & 63, wid = t >> 6;
  int wr = wid >> 1, wc = wid & 1;
  int lr = l & 15, lk16 = (l >> 4) * 16;

  int nwg = gridDim.x, wg = blockIdx.x;
  int q = nwg >> 3, r = nwg & 7;
  int xcd = wg & 7, loc = wg >> 3;
  int swz = (xcd < r ? xcd * (q + 1) : r * (q + 1) + (xcd - r) * q) + loc;
  int mblk = swz / gridN;
  int nblk = swz - mblk * gridN;
  int mb = mblk * 128, nb = nblk * 128;
  int NT = K >> 6;
  const u16* Ab = A  + (size_t)mb * K;
  const u16* Bb = Wt + (size_t)nb * K;

  int srow = t >> 3;
  int skb  = (t & 7) * 16;

  auto stage = [&](int kt, int b) {
    const u16* As = Ab + kt * 64;
    char* LD = (char*)&lds[b][0];
#pragma unroll
    for (int j = 0; j < 4; ++j) {
      int row = j * 32 + srow;
      int kb  = skb ^ ((row & 7) << 4);
      gload16(As + (size_t)row * K + (kb >> 1), LD + j * 4096 + t * 16);
    }
    const u16* Bs = Bb + kt * 64;
#pragma unroll
    for (int j = 0; j < 4; ++j) {
      int row = j * 32 + srow;
      int kb  = skb ^ ((row & 7) << 4);
      gload16(Bs + (size_t)row * K + (kb >> 1), LD + BTILE + j * 4096 + t * 16);
    }
  };

  f32x4 acc[4][4] = {};

  auto tile = [&](int b) {
    const char* LA = (const char*)&lds[b][0];
    const char* LB = LA + BTILE;
    bf16x8 bfr[2][4], afr[2][4];
#pragma unroll
    for (int ks = 0; ks < 2; ++ks)
#pragma unroll
      for (int n = 0; n < 4; ++n) {
        int rr = wc * 64 + n * 16 + lr;
        int kb = (ks * 64 + lk16) ^ ((rr & 7) << 4);
        bfr[ks][n] = *(const bf16x8*)(LB + rr * 128 + kb);
      }
#pragma unroll
    for (int ks = 0; ks < 2; ++ks)
#pragma unroll
      for (int m = 0; m < 4; ++m) {
        int rr = wr * 64 + m * 16 + lr;
        int kb = (ks * 64 + lk16) ^ ((rr & 7) << 4);
        afr[ks][m] = *(const bf16x8*)(LA + rr * 128 + kb);
      }
    __builtin_amdgcn_s_setprio(1);
#pragma unroll
    for (int ks = 0; ks < 2; ++ks)
#pragma unroll
      for (int m = 0; m < 4; ++m)
#pragma unroll
        for (int n = 0; n < 4; ++n)
          acc[m][n] = __builtin_amdgcn_mfma_f32_16x16x32_bf16(
              afr[ks][m], bfr[ks][n], acc[m][n], 0, 0, 0);
    __builtin_amdgcn_s_setprio(0);
  };

  stage(0, 0);
  stage(1, 1);
  asm volatile("s_waitcnt vmcnt(8)" ::: "memory");
  __builtin_amdgcn_s_barrier();
  __builtin_amdgcn_sched_barrier(0);

  for (int kt = 0; kt < NT; kt += 2) {
#pragma unroll
    for (int sub = 0; sub < 2; ++sub) {
      tile(sub);
      asm volatile("s_waitcnt lgkmcnt(0)" ::: "memory");
      __builtin_amdgcn_s_barrier();
      __builtin_amdgcn_sched_barrier(0);
      if (kt + 2 + sub < NT) {
        stage(kt + 2 + sub, sub);
        asm volatile("s_waitcnt vmcnt(8)" ::: "memory");
      } else {
        asm volatile("s_waitcnt vmcnt(0)" ::: "memory");
      }
      __builtin_amdgcn_s_barrier();
      __builtin_amdgcn_sched_barrier(0);
    }
  }

  int r0 = (l >> 4) * 4;
#pragma unroll
  for (int m = 0; m < 4; ++m) {
    int gr = mb + wr * 64 + m * 16 + r0;
#pragma unroll
    for (int n = 0; n < 4; ++n) {
      int gc = nb + wc * 64 + n * 16 + lr;
      float bv = 0.f;
      if constexpr (EPI == 0) bv = bias[gc];
#pragma unroll
      for (int rr = 0; rr < 4; ++rr) {
        int grr = gr + rr;
        float v = acc[m][n][rr] + bv;
        size_t o = (size_t)grr * N + gc;
        if constexpr (EPI == 0) {
          outf[o] = v + resid[o];
        } else {
          if (grr < Mv) outf[o] = v;
        }
      }
    }
  }
}

// ---------------- MLP2 split-K=2: 128x128 tiles, f32 partial slices ----------------
__global__ __launch_bounds__(256, 2) void k_gemm3p(const u16* __restrict__ A,
                                                   const u16* __restrict__ Wt,
                                                   float* __restrict__ pbuf,
                                                   int N, int K, int gridN) {
  constexpr int KS = 2;
  constexpr int BTILE = 16384;
  __shared__ u16 lds[2][128 * 64 * 2];

  int t = threadIdx.x, l = t & 63, wid = t >> 6;
  int wr = wid >> 1, wc = wid & 1;
  int lr = l & 15, lk16 = (l >> 4) * 16;

  int nwg = gridDim.x, wg = blockIdx.x;
  int q = nwg >> 3, r = nwg & 7;
  int xcd = wg & 7, loc = wg >> 3;
  int swz = (xcd < r ? xcd * (q + 1) : r * (q + 1) + (xcd - r) * q) + loc;
  int mblk = swz / (gridN * KS);
  int rest = swz - mblk * (gridN * KS);
  int nblk = rest / KS;
  int kz   = rest - nblk * KS;
  int mb = mblk * 128, nb = nblk * 128;
  int Ksub = K / KS;
  int NT = Ksub >> 6;
  const u16* Ab = A  + (size_t)mb * K + (size_t)kz * Ksub;
  const u16* Bb = Wt + (size_t)nb * K + (size_t)kz * Ksub;

  int srow = t >> 3;
  int skb  = (t & 7) * 16;

  auto stage = [&](int kt, int b) {
    const u16* As = Ab + kt * 64;
    char* LD = (char*)&lds[b][0];
#pragma unroll
    for (int j = 0; j < 4; ++j) {
      int row = j * 32 + srow;
      int kb  = skb ^ ((row & 7) << 4);
      gload16(As + (size_t)row * K + (kb >> 1), LD + j * 4096 + t * 16);
    }
    const u16* Bs = Bb + kt * 64;
#pragma unroll
    for (int j = 0; j < 4; ++j) {
      int row = j * 32 + srow;
      int kb  = skb ^ ((row & 7) << 4);
      gload16(Bs + (size_t)row * K + (kb >> 1), LD + BTILE + j * 4096 + t * 16);
    }
  };

  f32x4 acc[4][4] = {};

  auto tile = [&](int b) {
    const char* LA = (const char*)&lds[b][0];
    const char* LB = LA + BTILE;
    bf16x8 bfr[2][4], afr[2][4];
#pragma unroll
    for (int ks = 0; ks < 2; ++ks)
#pragma unroll
      for (int n = 0; n < 4; ++n) {
        int rr = wc * 64 + n * 16 + lr;
        int kb = (ks * 64 + lk16) ^ ((rr & 7) << 4);
        bfr[ks][n] = *(const bf16x8*)(LB + rr * 128 + kb);
      }
#pragma unroll
    for (int ks = 0; ks < 2; ++ks)
#pragma unroll
      for (int m = 0; m < 4; ++m) {
        int rr = wr * 64 + m * 16 + lr;
        int kb = (ks * 64 + lk16) ^ ((rr & 7) << 4);
        afr[ks][m] = *(const bf16x8*)(LA + rr * 128 + kb);
      }
    __builtin_amdgcn_s_setprio(1);
#pragma unroll
    for (int ks = 0; ks < 2; ++ks)
#pragma unroll
      for (int m = 0; m < 4; ++m)
#pragma unroll
        for (int n = 0; n < 4; ++n)
          acc[m][n] = __builtin_amdgcn_mfma_f32_16x16x32_bf16(
              afr[ks][m], bfr[ks][n], acc[m][n], 0, 0, 0);
    __builtin_amdgcn_s_setprio(0);
  };

  stage(0, 0);
  stage(1, 1);
  asm volatile("s_waitcnt vmcnt(8)" ::: "memory");
  __builtin_amdgcn_s_barrier();
  __builtin_amdgcn_sched_barrier(0);

  for (int kt = 0; kt < NT; kt += 2) {
#pragma unroll
    for (int sub = 0; sub < 2; ++sub) {
      tile(sub);
      asm volatile("s_waitcnt lgkmcnt(0)" ::: "memory");
      __builtin_amdgcn_s_barrier();
      __builtin_amdgcn_sched_barrier(0);
      if (kt + 2 + sub < NT) {
        stage(kt + 2 + sub, sub);
        asm volatile("s_waitcnt vmcnt(8)" ::: "memory");
      } else {
        asm volatile("s_waitcnt vmcnt(0)" ::: "memory");
      }
      __builtin_amdgcn_s_barrier();
      __builtin_amdgcn_sched_barrier(0);
    }
  }

  float* pb = pbuf + (size_t)kz * PB2;
  int r0 = (l >> 4) * 4;
#pragma unroll
  for (int m = 0; m < 4; ++m) {
    int gr = mb + wr * 64 + m * 16 + r0;
#pragma unroll
    for (int n = 0; n < 4; ++n) {
      int gc = nb + wc * 64 + n * 16 + lr;
#pragma unroll
      for (int rr = 0; rr < 4; ++rr)
        pb[(size_t)(gr + rr) * N + gc] = acc[m][n][rr];
    }
  }
}

// ---------------- head GEMM split-K=8: 128x128 tiles, f32 partial slices ----------------
__global__ __launch_bounds__(256, 2) void k_gemm3sk(const u16* __restrict__ A,
                                                    const u16* __restrict__ Wt,
                                                    float* __restrict__ pbuf,
                                                    int N, int K) {
  constexpr int KS = 8;
  constexpr int BTILE = 16384;
  __shared__ u16 lds[2][128 * 64 * 2];

  int t = threadIdx.x, l = t & 63, wid = t >> 6;
  int wr = wid >> 1, wc = wid & 1;
  int lr = l & 15, lk16 = (l >> 4) * 16;

  int nwg = gridDim.x, wg = blockIdx.x;
  int q = nwg >> 3, r = nwg & 7;
  int xcd = wg & 7, loc = wg >> 3;
  int swz = (xcd < r ? xcd * (q + 1) : r * (q + 1) + (xcd - r) * q) + loc;
  int mblk = swz / KS;
  int kz   = swz - mblk * KS;
  int mb = mblk * 128, nb = 0;
  int Ksub = K / KS;
  int NT = Ksub >> 6;               // = 2
  const u16* Ab = A  + (size_t)mb * K + (size_t)kz * Ksub;
  const u16* Bb = Wt + (size_t)kz * Ksub;

  int srow = t >> 3;
  int skb  = (t & 7) * 16;

  auto stage = [&](int kt, int b) {
    const u16* As = Ab + kt * 64;
    char* LD = (char*)&lds[b][0];
#pragma unroll
    for (int j = 0; j < 4; ++j) {
      int row = j * 32 + srow;
      int kb  = skb ^ ((row & 7) << 4);
      gload16(As + (size_t)row * K + (kb >> 1), LD + j * 4096 + t * 16);
    }
    const u16* Bs = Bb + kt * 64;
#pragma unroll
    for (int j = 0; j < 4; ++j) {
      int row = j * 32 + srow;
      int kb  = skb ^ ((row & 7) << 4);
      gload16(Bs + (size_t)row * K + (kb >> 1), LD + BTILE + j * 4096 + t * 16);
    }
  };

  f32x4 acc[4][4] = {};

  auto tile = [&](int b) {
    const char* LA = (const char*)&lds[b][0];
    const char* LB = LA + BTILE;
    bf16x8 bfr[2][4], afr[2][4];
#pragma unroll
    for (int ks = 0; ks < 2; ++ks)
#pragma unroll
      for (int n = 0; n < 4; ++n) {
        int rr = wc * 64 + n * 16 + lr;
        int kb = (ks * 64 + lk16) ^ ((rr & 7) << 4);
        bfr[ks][n] = *(const bf16x8*)(LB + rr * 128 + kb);
      }
#pragma unroll
    for (int ks = 0; ks < 2; ++ks)
#pragma unroll
      for (int m = 0; m < 4; ++m) {
        int rr = wr * 64 + m * 16 + lr;
        int kb = (ks * 64 + lk16) ^ ((rr & 7) << 4);
        afr[ks][m] = *(const bf16x8*)(LA + rr * 128 + kb);
      }
#pragma unroll
    for (int ks = 0; ks < 2; ++ks)
#pragma unroll
      for (int m = 0; m < 4; ++m)
#pragma unroll
        for (int n = 0; n < 4; ++n)
          acc[m][n] = __builtin_amdgcn_mfma_f32_16x16x32_bf16(
              afr[ks][m], bfr[ks][n], acc[m][n], 0, 0, 0);
  };

  stage(0, 0);
  stage(1, 1);
  asm volatile("s_waitcnt vmcnt(8)" ::: "memory");
  __builtin_amdgcn_s_barrier();
  __builtin_amdgcn_sched_barrier(0);

  for (int kt = 0; kt < NT; kt += 2) {
#pragma unroll
    for (int sub = 0; sub < 2; ++sub) {
      tile(sub);
      asm volatile("s_waitcnt lgkmcnt(0)" ::: "memory");
      __builtin_amdgcn_s_barrier();
      __builtin_amdgcn_sched_barrier(0);
      if (kt + 2 + sub < NT) {
        stage(kt + 2 + sub, sub);
        asm volatile("s_waitcnt vmcnt(8)" ::: "memory");
      } else {
        asm volatile("s_waitcnt vmcnt(0)" ::: "memory");
      }
      __builtin_amdgcn_s_barrier();
      __builtin_amdgcn_sched_barrier(0);
    }
  }

  float* pb = pbuf + (size_t)kz * PH;
  int r0 = (l >> 4) * 4;
#pragma unroll
  for (int m = 0; m < 4; ++m) {
    int gr = mb + wr * 64 + m * 16 + r0;
#pragma unroll
    for (int n = 0; n < 4; ++n) {
      int gc = nb + wc * 64 + n * 16 + lr;
#pragma unroll
      for (int rr = 0; rr < 4; ++rr)
        pb[(size_t)(gr + rr) * N + gc] = acc[m][n][rr];
    }
  }
}

// head reduce: out[i] = sum over 8 slices (exact-fit grid: MV*VV threads)
__global__ __launch_bounds__(256) void k_redhead(const float* __restrict__ pb,
                                                 float* __restrict__ out) {
  int i = blockIdx.x * 256 + threadIdx.x;
  float s = 0.f;
#pragma unroll
  for (int z = 0; z < 8; ++z) s += pb[(size_t)z * PH + i];
  out[i] = s;
}

// ---------------- V transpose: qkv[., 2048+h*64+d] -> vt[b,h,d,t] ----------------
__global__ __launch_bounds__(256) void k_vtrans(const u16* __restrict__ qkv,
                                                u16* __restrict__ vt) {
  __shared__ u16 tile[64][66];
  int bh = blockIdx.y;
  int b = bh >> 4, h = bh & 15;
  int t0 = blockIdx.x * 64;
  int t = threadIdx.x;
  int r = t >> 4, c4 = (t & 15) * 4;
#pragma unroll
  for (int i = 0; i < 4; ++i) {
    int tt = r + i * 16;
    int trow = t0 + tt;
    int srow = b * TT + (trow < TT ? trow : TT - 1);
    ushort4 v = *(const ushort4*)(qkv + (size_t)srow * 3072 + 2048 + h * 64 + c4);
    tile[tt][c4 + 0] = v.x; tile[tt][c4 + 1] = v.y;
    tile[tt][c4 + 2] = v.z; tile[tt][c4 + 3] = v.w;
  }
  __syncthreads();
#pragma unroll
  for (int i = 0; i < 4; ++i) {
    int d = r + i * 16;
    ushort4 o;
    o.x = (t0 + c4 + 0 < TT) ? tile[c4 + 0][d] : (u16)0;
    o.y = (t0 + c4 + 1 < TT) ? tile[c4 + 1][d] : (u16)0;
    o.z = (t0 + c4 + 2 < TT) ? tile[c4 + 2][d] : (u16)0;
    o.w = (t0 + c4 + 3 < TT) ? tile[c4 + 3][d] : (u16)0;
    *(ushort4*)(vt + ((size_t)bh * 64 + d) * TP + t0 + c4) = o;
  }
}

// ---------------- flash attention: block = (b,h, 128 q rows), 8 waves ----------------
__global__ __launch_bounds__(512, 2) void k_attn2(const u16* __restrict__ qkv,
                                                  const u16* __restrict__ vt,
                                                  u16* __restrict__ y) {
  __shared__ u16 Kb[2][64 * 64];
  __shared__ u16 Vb[2][64 * 64];
  __shared__ u16 Pb[8][16 * 64];
  int t = threadIdx.x, l = t & 63, w = t >> 6;

  int nwg = gridDim.x, wg = blockIdx.x;
  int swz = (wg & 7) * (nwg >> 3) + (wg >> 3);
  int bh = swz >> 2, qt = swz & 3;
  int b = bh >> 4, h = bh & 15;
  int q0 = qt * 128;
  int lr = l & 15, lg = l >> 4, lk8 = lg * 8;

  const float ISC = 0.125f;

  bf16x8 Qa[2];
  {
    int qs = q0 + w * 16 + lr;
    const u16* qp = qkv + (size_t)(b * TT + (qs < TT ? qs : TT - 1)) * 3072 + h * 64;
    Qa[0] = *(const bf16x8*)(qp + lk8);
    Qa[1] = *(const bf16x8*)(qp + 32 + lk8);
  }

  int NT = (q0 + 128) >> 6;

  int srow = w * 8 + (l >> 3);
  int sb16 = (l & 7) * 16;
  int bcol = sb16 ^ ((srow & 7) << 4);
  const u16* Ksrc = qkv + 1024 + h * 64;
  const char* Vsrc = (const char*)(vt + ((size_t)bh * 64 + srow) * TP);

  auto stage = [&](int kt, int buf) {
    int kv0 = kt * 64;
    int kvr = kv0 + srow;
    int krow = b * TT + (kvr < TT ? kvr : TT - 1);
    gload16((const char*)(Ksrc + (size_t)krow * 3072) + bcol, (char*)&Kb[buf][0] + t * 16);
    gload16(Vsrc + kv0 * 2 + bcol, (char*)&Vb[buf][0] + t * 16);
  };

  f32x4 O[4] = {};
  float m_[4], s_[4];
#pragma unroll
  for (int r = 0; r < 4; ++r) { m_[r] = -1e30f; s_[r] = 0.f; }

  stage(0, 0);
  for (int kt = 0; kt < NT; ++kt) {
    int buf = kt & 1;
    if (kt + 1 < NT) {
      stage(kt + 1, buf ^ 1);
      asm volatile("s_waitcnt vmcnt(2)" ::: "memory");
    } else {
      asm volatile("s_waitcnt vmcnt(0)" ::: "memory");
    }
    __builtin_amdgcn_s_barrier();

    int kv0 = kt * 64;
    f32x4 S[4];
    const char* LK = (const char*)&Kb[buf][0];
#pragma unroll
    for (int j = 0; j < 4; ++j) {
      f32x4 a = {};
#pragma unroll
      for (int ks = 0; ks < 2; ++ks) {
        int row = j * 16 + lr;
        int kb = ((ks * 32 + lk8) * 2) ^ ((row & 7) << 4);
        bf16x8 kf = *(const bf16x8*)(LK + row * 128 + kb);
        a = __builtin_amdgcn_mfma_f32_16x16x32_bf16(Qa[ks], kf, a, 0, 0, 0);
      }
      S[j] = a;
    }
    int qbase = q0 + w * 16 + lg * 4;
#pragma unroll
    for (int j = 0; j < 4; ++j) {
      int kv = kv0 + j * 16 + lr;
#pragma unroll
      for (int r = 0; r < 4; ++r) {
        bool valid = (kv <= qbase + r) && (kv < TT);
        S[j][r] = valid ? S[j][r] : -1e30f;
      }
    }
    float mx[4];
#pragma unroll
    for (int r = 0; r < 4; ++r)
      mx[r] = fmaxf(fmaxf(S[0][r], S[1][r]), fmaxf(S[2][r], S[3][r]));
#pragma unroll
    for (int r = 0; r < 4; ++r) {
      mx[r] = fmaxf(mx[r], __shfl_xor(mx[r], 1));
      mx[r] = fmaxf(mx[r], __shfl_xor(mx[r], 2));
      mx[r] = fmaxf(mx[r], __shfl_xor(mx[r], 4));
      mx[r] = fmaxf(mx[r], __shfl_xor(mx[r], 8));
    }
    float sc[4];
#pragma unroll
    for (int r = 0; r < 4; ++r) {
      float mn = fmaxf(m_[r], mx[r]);
      sc[r] = __expf((m_[r] - mn) * ISC);
      m_[r] = mn;
      s_[r] *= sc[r];
    }
#pragma unroll
    for (int j = 0; j < 4; ++j)
#pragma unroll
      for (int r = 0; r < 4; ++r) O[j][r] *= sc[r];
    float rs[4] = {0.f, 0.f, 0.f, 0.f};
    char* LP = (char*)&Pb[w][0];
#pragma unroll
    for (int j = 0; j < 4; ++j) {
#pragma unroll
      for (int r = 0; r < 4; ++r) {
        float p = __expf((S[j][r] - m_[r]) * ISC);
        rs[r] += p;
        int row = lg * 4 + r;
        int addr = (row * 128 + (j * 16 + lr) * 2) ^ ((row & 7) << 4);
        *(u16*)(LP + addr) = f2bf(p);
      }
    }
#pragma unroll
    for (int r = 0; r < 4; ++r) {
      rs[r] += __shfl_xor(rs[r], 1);
      rs[r] += __shfl_xor(rs[r], 2);
      rs[r] += __shfl_xor(rs[r], 4);
      rs[r] += __shfl_xor(rs[r], 8);
      s_[r] += rs[r];
    }
    bf16x8 Pa[2];
#pragma unroll
    for (int ks = 0; ks < 2; ++ks) {
      int addr = (lr * 128 + (ks * 32 + lk8) * 2) ^ ((lr & 7) << 4);
      Pa[ks] = *(const bf16x8*)(LP + addr);
    }
    const char* LV = (const char*)&Vb[buf][0];
#pragma unroll
    for (int j = 0; j < 4; ++j) {
#pragma unroll
      for (int ks = 0; ks < 2; ++ks) {
        int row = j * 16 + lr;
        int kb = ((ks * 32 + lk8) * 2) ^ ((row & 7) << 4);
        bf16x8 vf = *(const bf16x8*)(LV + row * 128 + kb);
        O[j] = __builtin_amdgcn_mfma_f32_16x16x32_bf16(Pa[ks], vf, O[j], 0, 0, 0);
      }
    }
    asm volatile("s_waitcnt lgkmcnt(0)" ::: "memory");
    __builtin_amdgcn_s_barrier();
  }

  int qs0 = q0 + w * 16 + lg * 4;
#pragma unroll
  for (int r = 0; r < 4; ++r) {
    float inv = 1.0f / s_[r];
    int qs = qs0 + r;
    if (qs < TT) {
      u16* yp = y + (size_t)(b * TT + qs) * CC + h * 64;
#pragma unroll
      for (int j = 0; j < 4; ++j)
        yp[j * 16 + lr] = f2bf(O[j][r] * inv);
    }
  }
}

// ---------------- host ----------------
extern "C" void kernel_launch(void* const* d_in, const int* in_sizes, int n_in,
                              void* d_out, int out_size, void* d_ws, size_t ws_size,
                              hipStream_t stream) {
  (void)in_sizes; (void)n_in; (void)out_size;
  const int*   idx  = (const int*)  d_in[0];
  const float* tok  = (const float*)d_in[1];
  const float* pos  = (const float*)d_in[2];
  const float* ln1w = (const float*)d_in[3];
  const float* ln1b = (const float*)d_in[4];
  const float* Wq   = (const float*)d_in[5];
  const float* bq   = (const float*)d_in[6];
  const float* Wk   = (const float*)d_in[7];
  const float* bk   = (const float*)d_in[8];
  const float* Wv   = (const float*)d_in[9];
  const float* bv   = (const float*)d_in[10];
  const float* Wp   = (const float*)d_in[11];
  const float* bp   = (const float*)d_in[12];
  const float* ln2w = (const float*)d_in[13];
  const float* ln2b = (const float*)d_in[14];
  const float* W1   = (const float*)d_in[15];
  const float* b1   = (const float*)d_in[16];
  const float* W2   = (const float*)d_in[17];
  const float* b2   = (const float*)d_in[18];
  const float* lnfw = (const float*)d_in[19];
  const float* lnfb = (const float*)d_in[20];
  const float* headw= (const float*)d_in[21];
  float* out = (float*)d_out;

  char* p = (char*)d_ws;
  auto alloc = [&](size_t bytes) { char* r = p; p += (bytes + 255) & ~(size_t)255; return r; };
  u16*   wqkv_t = (u16*)  alloc((size_t)LL * 3 * CC * CC * 2);
  u16*   wp_t   = (u16*)  alloc((size_t)LL * CC * CC * 2);
  u16*   w1_t   = (u16*)  alloc((size_t)LL * FF_ * CC * 2);
  u16*   w2_t   = (u16*)  alloc((size_t)LL * CC * FF_ * 2);
  u16*   headb  = (u16*)  alloc((size_t)VV * CC * 2);
  float* bqkv   = (float*)alloc((size_t)LL * 3 * CC * 4);
  float* x      = (float*)alloc((size_t)MP * CC * 4);
  u16*   hbuf   = (u16*)  alloc((size_t)MP * CC * 2);
  u16*   qkv    = (u16*)  alloc((size_t)MP * 3 * CC * 2);
  u16*   vt     = (u16*)  alloc((size_t)NB * HH * 64 * TP * 2);
  u16*   ybuf   = (u16*)  alloc((size_t)MP * CC * 2);
  u16*   ffb    = (u16*)  alloc((size_t)MP * FF_ * 2);
  float* pbuf   = (float*)alloc((size_t)8 * PH * 4);    // 16 MB head split-K partials
  float* pbuf2  = (float*)alloc((size_t)2 * PB2 * 4);   // 32 MB mlp2 split-K partials
  bool havePB = ((size_t)(p - (char*)d_ws) <= ws_size);

  // mega prologue: embed + all weight transposes + head cast + bias pack
  int prepBlocks = MP + 3 * 8192 + (VV * CC + LL * 3 * CC + 255) / 256;
  k_prep_all<<<prepBlocks, 256, 0, stream>>>(idx, tok, pos, x, Wq, Wk, Wv, Wp, W1, W2,
                                             headw, bq, bk, bv,
                                             wqkv_t, wp_t, w1_t, w2_t, headb, bqkv);
  k_ln<<<MP / 4, 256, 0, stream>>>(x, ln1w, ln1b, hbuf);       // layer 0 ln1

  for (int l = 0; l < LL; ++l) {
    const float* nw = (l < LL - 1) ? ln1w + (size_t)(l + 1) * CC : lnfw;
    const float* nb = (l < LL - 1) ? ln1b + (size_t)(l + 1) * CC : lnfb;
    // QKV: M=4096, N=3072, K=1024  (256x192 8-phase, 256 blocks = full fill)
    k_gemm5<1><<<16 * 16, 512, 0, stream>>>(hbuf, wqkv_t + (size_t)l * 3 * CC * CC,
                                            bqkv + (size_t)l * 3 * CC, qkv, 3 * CC, CC, 16);
    k_vtrans<<<dim3(8, NB * HH), 256, 0, stream>>>(qkv, vt);
    k_attn2<<<NB * HH * 4, 512, 0, stream>>>(qkv, vt, ybuf);
    // proj: M=4096, N=1024, K=1024  (128x128, resid-add into x)
    k_gemm3<0><<<32 * 8, 256, 0, stream>>>(ybuf, wp_t + (size_t)l * CC * CC,
                                           bp + (size_t)l * CC, x, x, CC, CC, 8, MP);
    k_ln<<<MP / 4, 256, 0, stream>>>(x, ln2w + (size_t)l * CC, ln2b + (size_t)l * CC, hbuf);
    // MLP1: M=4096, N=4096, K=1024, GELU  (256x256 8-phase)
    k_gemm4<2><<<16 * 16, 512, 0, stream>>>(hbuf, w1_t + (size_t)l * FF_ * CC,
                                            b1 + (size_t)l * FF_, ffb, FF_, CC, 16);
    if (havePB) {
      // MLP2: M=4096, N=1024, K=4096  split-K=2 (128x128, 512 blocks, 2/CU), f32 partials
      k_gemm3p<<<32 * 8 * 2, 256, 0, stream>>>(ffb, w2_t + (size_t)l * CC * FF_, pbuf2, CC, FF_, 8);
      // fused: x += p0+p1+b2 ; hbuf = LN_next(x)
      k_redln2<<<MP / 4, 256, 0, stream>>>(x, pbuf2, b2 + (size_t)l * CC, nw, nb, hbuf);
    } else {
      k_gemm3<0><<<32 * 8, 256, 0, stream>>>(ffb, w2_t + (size_t)l * CC * FF_,
                                             b2 + (size_t)l * CC, x, x, CC, FF_, 8, MP);
      k_ln<<<MP / 4, 256, 0, stream>>>(x, nw, nb, hbuf);
    }
  }

  if (havePB) {
    // head: split-K=8, 256 blocks full fill, then reduce
    k_gemm3sk<<<32 * 8, 256, 0, stream>>>(hbuf, headb, pbuf, VV, CC);
    k_redhead<<<(MV * VV) / 256, 256, 0, stream>>>(pbuf, out);
  } else {
    k_gemm3<3><<<32 * 1, 256, 0, stream>>>(hbuf, headb, nullptr, out, nullptr, VV, CC, 1, MV);
  }
}

// Round 14
// 1634.113 us; speedup vs baseline: 1.0030x; 1.0030x over previous
//
#include <hip/hip_runtime.h>
#include <hip/hip_bf16.h>

typedef unsigned short u16;
typedef unsigned int   u32;
typedef __attribute__((ext_vector_type(8))) __bf16 bf16x8;
typedef __attribute__((ext_vector_type(4))) float  f32x4;
typedef __attribute__((ext_vector_type(8))) unsigned short u16x8;

static constexpr int NB  = 8;      // batch
static constexpr int TT  = 511;    // seq len
static constexpr int CC  = 1024;   // model dim
static constexpr int HH  = 16;     // heads
static constexpr int LL  = 8;      // layers
static constexpr int VV  = 128;    // vocab
static constexpr int FF_ = 4096;   // ffn dim
static constexpr int MV  = NB * TT;   // 4088 valid rows
static constexpr int MP  = 4096;      // padded rows
static constexpr int TP  = 512;       // padded seq for vt
static constexpr size_t PH  = (size_t)MP * VV;   // head partial slice stride
static constexpr size_t PB2 = (size_t)MP * CC;   // mlp2 partial slice stride

#define DEVI static __device__ __forceinline__

DEVI u16 f2bf(float f) {
  u32 u = __builtin_bit_cast(u32, f);
  u = (u + 0x7fffu + ((u >> 16) & 1u)) >> 16;
  return (u16)u;
}

DEVI void gload16(const void* g, void* lds) {
  auto gp = (const __attribute__((address_space(1))) u32*)(uintptr_t)g;
  auto lp = (__attribute__((address_space(3))) u32*)(uintptr_t)lds;
  __builtin_amdgcn_global_load_lds(gp, lp, 16, 0, 0);
}

// ---- conflict-free 64x64 transpose tile: in [K][N] f32 (at kb,nb) -> out [N][K] bf16 ----
// tile[n][kc] dwords (kc = k/2, row stride 33 dwords): write banks (n+kc)%32 spread 2-way;
// read 4 dwords/row also 2-way. Output is 16B u16x8 store.
DEVI void trans_tile(u32* tile, const float* __restrict__ in, int N,
                     u16* __restrict__ out, int K, int t) {
  int c4 = (t & 15) * 4;
  int rp = t >> 4;
#pragma unroll
  for (int i = 0; i < 2; ++i) {
    int k = (rp + i * 16) * 2;
    float4 a = *(const float4*)(in + (size_t)k * N + c4);
    float4 b = *(const float4*)(in + (size_t)(k + 1) * N + c4);
    int kc = k >> 1;
    tile[(c4 + 0) * 33 + kc] = (u32)f2bf(a.x) | ((u32)f2bf(b.x) << 16);
    tile[(c4 + 1) * 33 + kc] = (u32)f2bf(a.y) | ((u32)f2bf(b.y) << 16);
    tile[(c4 + 2) * 33 + kc] = (u32)f2bf(a.z) | ((u32)f2bf(b.z) << 16);
    tile[(c4 + 3) * 33 + kc] = (u32)f2bf(a.w) | ((u32)f2bf(b.w) << 16);
  }
  __syncthreads();
  int k8 = (t & 7) * 8;
  int kc4 = k8 >> 1;
#pragma unroll
  for (int i = 0; i < 2; ++i) {
    int n = (t >> 3) + i * 32;
    u32 d[4];
#pragma unroll
    for (int c = 0; c < 4; ++c) d[c] = tile[n * 33 + kc4 + c];
    u16x8 o;
#pragma unroll
    for (int c = 0; c < 4; ++c) { o[2 * c] = (u16)d[c]; o[2 * c + 1] = (u16)(d[c] >> 16); }
    *(u16x8*)(out + (size_t)n * K + k8) = o;
  }
}

// ---------------- mega prologue: embed + all weight transposes + head cast + bias pack ----
// block ranges: [0,MP) embed ; [MP, MP+8192) QKV/Wp tiles ; +8192 W1 ; +8192 W2 ; rest prep
__global__ __launch_bounds__(256) void k_prep_all(const int* __restrict__ idx,
                                                  const float* __restrict__ tok,
                                                  const float* __restrict__ pos,
                                                  float* __restrict__ x,
                                                  const float* __restrict__ Wq,
                                                  const float* __restrict__ Wk,
                                                  const float* __restrict__ Wv,
                                                  const float* __restrict__ Wp,
                                                  const float* __restrict__ W1,
                                                  const float* __restrict__ W2,
                                                  const float* __restrict__ headw,
                                                  const float* __restrict__ bq,
                                                  const float* __restrict__ bk,
                                                  const float* __restrict__ bv,
                                                  u16* __restrict__ wqkv_t,
                                                  u16* __restrict__ wp_t,
                                                  u16* __restrict__ w1_t,
                                                  u16* __restrict__ w2_t,
                                                  u16* __restrict__ headb,
                                                  float* __restrict__ bqkv) {
  __shared__ u32 tile[64 * 33];
  int bid = blockIdx.x, t = threadIdx.x;
  if (bid < MP) {                      // ---- embedding ----
    int row = bid;
    int c4 = t * 4;
    if (row >= MV) {
      *(float4*)(x + (size_t)row * CC + c4) = make_float4(0.f, 0.f, 0.f, 0.f);
      return;
    }
    int tt = row % TT;
    int tid = idx[row];
    float4 a = *(const float4*)(tok + (size_t)tid * CC + c4);
    float4 p = *(const float4*)(pos + (size_t)tt * CC + c4);
    a.x += p.x; a.y += p.y; a.z += p.z; a.w += p.w;
    *(float4*)(x + (size_t)row * CC + c4) = a;
    return;
  }
  bid -= MP;
  if (bid < 8192) {                    // ---- Wq/Wk/Wv/Wp (CCxCC) ----
    int which = bid >> 11, rem = bid & 2047;
    int lyr = rem >> 8, ti = rem & 255;
    int nb = (ti & 15) * 64, kb = (ti >> 4) * 64;
    const float* in; u16* out;
    size_t sq = (size_t)CC * CC;
    if (which == 0)      { in = Wq + lyr * sq; out = wqkv_t + lyr * 3 * sq; }
    else if (which == 1) { in = Wk + lyr * sq; out = wqkv_t + lyr * 3 * sq + sq; }
    else if (which == 2) { in = Wv + lyr * sq; out = wqkv_t + lyr * 3 * sq + 2 * sq; }
    else                 { in = Wp + lyr * sq; out = wp_t + lyr * sq; }
    trans_tile(tile, in + (size_t)kb * CC + nb, CC, out + (size_t)nb * CC + kb, CC, t);
    return;
  }
  bid -= 8192;
  if (bid < 8192) {                    // ---- W1 [CC][FF] -> [FF][CC] ----
    int lyr = bid >> 10, ti = bid & 1023;
    int nb = (ti & 63) * 64, kb = (ti >> 6) * 64;
    trans_tile(tile, W1 + (size_t)lyr * CC * FF_ + (size_t)kb * FF_ + nb, FF_,
               w1_t + (size_t)lyr * FF_ * CC + (size_t)nb * CC + kb, CC, t);
    return;
  }
  bid -= 8192;
  if (bid < 8192) {                    // ---- W2 [FF][CC] -> [CC][FF] ----
    int lyr = bid >> 10, ti = bid & 1023;
    int nb = (ti & 15) * 64, kb = (ti >> 4) * 64;
    trans_tile(tile, W2 + (size_t)lyr * FF_ * CC + (size_t)kb * CC + nb, CC,
               w2_t + (size_t)lyr * CC * FF_ + (size_t)nb * FF_ + kb, FF_, t);
    return;
  }
  bid -= 8192;
  {                                    // ---- head cast + qkv bias pack ----
    int i = bid * 256 + t;
    if (i < VV * CC) {
      headb[i] = f2bf(headw[i]);
    } else {
      int j = i - VV * CC;
      if (j < LL * 3 * CC) {
        int l = j / (3 * CC), c = j % (3 * CC);
        float v = (c < CC) ? bq[l * CC + c] : (c < 2 * CC) ? bk[l * CC + c - CC] : bv[l * CC + c - 2 * CC];
        bqkv[j] = v;
      }
    }
  }
}

// ---------------- layernorm: f32 in -> bf16 out ----------------
__global__ __launch_bounds__(256) void k_ln(const float* __restrict__ x,
                                            const float* __restrict__ w,
                                            const float* __restrict__ b,
                                            u16* __restrict__ out) {
  int wid = threadIdx.x >> 6, l = threadIdx.x & 63;
  int row = blockIdx.x * 4 + wid;
  const float* xr = x + (size_t)row * CC;
  float4 v[4];
  float s = 0.f, sq = 0.f;
#pragma unroll
  for (int i = 0; i < 4; ++i) {
    v[i] = *(const float4*)(xr + (i * 64 + l) * 4);
    s  += v[i].x + v[i].y + v[i].z + v[i].w;
    sq += v[i].x * v[i].x + v[i].y * v[i].y + v[i].z * v[i].z + v[i].w * v[i].w;
  }
#pragma unroll
  for (int o = 32; o; o >>= 1) { s += __shfl_xor(s, o); sq += __shfl_xor(sq, o); }
  float mean = s * (1.f / CC);
  float var  = sq * (1.f / CC) - mean * mean;
  float rs = rsqrtf(var + 1e-5f);
#pragma unroll
  for (int i = 0; i < 4; ++i) {
    int c = (i * 64 + l) * 4;
    float4 wv = *(const float4*)(w + c);
    float4 bv = *(const float4*)(b + c);
    ushort4 o4;
    o4.x = f2bf((v[i].x - mean) * rs * wv.x + bv.x);
    o4.y = f2bf((v[i].y - mean) * rs * wv.y + bv.y);
    o4.z = f2bf((v[i].z - mean) * rs * wv.z + bv.z);
    o4.w = f2bf((v[i].w - mean) * rs * wv.w + bv.w);
    *(ushort4*)(out + (size_t)row * CC + c) = o4;
  }
}

// ---------------- fused: x += p0+p1+bias ; out = LN(x)*w + b ----------------
__global__ __launch_bounds__(256) void k_redln2(float* __restrict__ x,
                                                const float* __restrict__ pb,
                                                const float* __restrict__ bias,
                                                const float* __restrict__ w,
                                                const float* __restrict__ b,
                                                u16* __restrict__ out) {
  int wid = threadIdx.x >> 6, l = threadIdx.x & 63;
  int row = blockIdx.x * 4 + wid;
  float* xr = x + (size_t)row * CC;
  const float* pr = pb + (size_t)row * CC;
  float4 v[4];
  float s = 0.f, sq = 0.f;
#pragma unroll
  for (int i = 0; i < 4; ++i) {
    int c = (i * 64 + l) * 4;
    float4 xv = *(const float4*)(xr + c);
    float4 p0 = *(const float4*)(pr + c);
    float4 p1 = *(const float4*)(pr + PB2 + c);
    float4 bb = *(const float4*)(bias + c);
    v[i].x = xv.x + p0.x + p1.x + bb.x;
    v[i].y = xv.y + p0.y + p1.y + bb.y;
    v[i].z = xv.z + p0.z + p1.z + bb.z;
    v[i].w = xv.w + p0.w + p1.w + bb.w;
    *(float4*)(xr + c) = v[i];
    s  += v[i].x + v[i].y + v[i].z + v[i].w;
    sq += v[i].x * v[i].x + v[i].y * v[i].y + v[i].z * v[i].z + v[i].w * v[i].w;
  }
#pragma unroll
  for (int o = 32; o; o >>= 1) { s += __shfl_xor(s, o); sq += __shfl_xor(sq, o); }
  float mean = s * (1.f / CC);
  float var  = sq * (1.f / CC) - mean * mean;
  float rs = rsqrtf(var + 1e-5f);
#pragma unroll
  for (int i = 0; i < 4; ++i) {
    int c = (i * 64 + l) * 4;
    float4 wv = *(const float4*)(w + c);
    float4 bv = *(const float4*)(b + c);
    ushort4 o4;
    o4.x = f2bf((v[i].x - mean) * rs * wv.x + bv.x);
    o4.y = f2bf((v[i].y - mean) * rs * wv.y + bv.y);
    o4.z = f2bf((v[i].z - mean) * rs * wv.z + bv.z);
    o4.w = f2bf((v[i].w - mean) * rs * wv.w + bv.w);
    *(ushort4*)(out + (size_t)row * CC + c) = o4;
  }
}

// ---------------- 256x256 8-wave 8-PHASE pipelined GEMM (MLP1) ----------------
// EPI: 1 = bf16 out ; 2 = bf16 out + exact GELU
template <int EPI>
__global__ __launch_bounds__(512, 1) void k_gemm4(const u16* __restrict__ A,
                                                  const u16* __restrict__ Wt,
                                                  const float* __restrict__ bias,
                                                  u16* __restrict__ outb,
                                                  int N, int K, int gridN) {
  __shared__ char lds[2][4][16384];
  int t = threadIdx.x, l = t & 63, wid = t >> 6;
  int wr = wid >> 2, wc = wid & 3;     // 2 x 4 wave grid; wave C = 128(M) x 64(N)
  int lr = l & 15, lk16 = (l >> 4) * 16;

  // XCD-bijective block swizzle (m-major)
  int nwg = gridDim.x, wg = blockIdx.x;
  int qq = nwg >> 3, r8 = nwg & 7;
  int xcd = wg & 7, loc = wg >> 3;
  int swz = (xcd < r8 ? xcd * (qq + 1) : r8 * (qq + 1) + (xcd - r8) * qq) + loc;
  int mblk = swz / gridN, nblk = swz - mblk * gridN;
  int mb = mblk * 256, nb = nblk * 256;
  int NT = K >> 6;
  const u16* Ab = A  + (size_t)mb * K;
  const u16* Bb = Wt + (size_t)nb * K;

  int srow = t >> 3, skb = (t & 7) * 16;

  auto stageH = [&](int kt, int ht) {
    int b = kt & 1;
    const u16* src = (ht < 2) ? Ab : Bb;
    int rowbase = (ht & 1) << 7;
    char* dst = &lds[b][ht][0];
    const u16* s0 = src + (size_t)rowbase * K + kt * 64;
#pragma unroll
    for (int j = 0; j < 2; ++j) {
      int row = j * 64 + srow;
      int kb = skb ^ ((row & 7) << 4);
      gload16(s0 + (size_t)row * K + (kb >> 1), dst + j * 8192 + t * 16);
    }
  };

  f32x4 acc[8][4] = {};

  stageH(0, 0); stageH(0, 1); stageH(0, 2); stageH(0, 3);
  stageH(1, 2); stageH(1, 0); stageH(1, 3);
  asm volatile("s_waitcnt vmcnt(6)" ::: "memory");
  __builtin_amdgcn_s_barrier();
  __builtin_amdgcn_sched_barrier(0);

  for (int kt = 0; kt < NT; kt += 2) {
    bool s2 = (kt + 2) < NT, s3 = (kt + 3) < NT;
#pragma unroll
    for (int half = 0; half < 2; ++half) {
      int buf = half;
      bf16x8 Bf[2][4];
#pragma unroll
      for (int q = 0; q < 4; ++q) {
        bf16x8 Af[2][2];
        if (q == 0) {
#pragma unroll
          for (int ks = 0; ks < 2; ++ks)
#pragma unroll
            for (int nf = 0; nf < 4; ++nf) {
              int grow = ((wc & 1) << 6) + nf * 16 + lr;
              int kb = (ks * 64 + lk16) ^ ((grow & 7) << 4);
              Bf[ks][nf] = *(const bf16x8*)(&lds[buf][2 + (wc >> 1)][0] + grow * 128 + kb);
            }
        }
#pragma unroll
        for (int ks = 0; ks < 2; ++ks)
#pragma unroll
          for (int dm = 0; dm < 2; ++dm) {
            int mf = q * 2 + dm;
            int grow = wr * 64 + (mf & 3) * 16 + lr;
            int kb = (ks * 64 + lk16) ^ ((grow & 7) << 4);
            Af[ks][dm] = *(const bf16x8*)(&lds[buf][mf >> 2][0] + grow * 128 + kb);
          }
        if (half == 0) {
          if (q == 0)      stageH(kt + 1, 1);
          else if (q == 1) { if (s2) stageH(kt + 2, 2); }
          else if (q == 2) { if (s2) stageH(kt + 2, 0); }
          else             { if (s2) stageH(kt + 2, 3); }
        } else {
          if (q == 0)      { if (s2) stageH(kt + 2, 1); }
          else if (q == 1) { if (s3) stageH(kt + 3, 2); }
          else if (q == 2) { if (s3) stageH(kt + 3, 0); }
          else             { if (s3) stageH(kt + 3, 3); }
        }
        __builtin_amdgcn_sched_barrier(0);
        __builtin_amdgcn_s_barrier();
        asm volatile("s_waitcnt lgkmcnt(0)" ::: "memory");
        __builtin_amdgcn_sched_barrier(0);
        __builtin_amdgcn_s_setprio(1);
#pragma unroll
        for (int ks = 0; ks < 2; ++ks)
#pragma unroll
          for (int dm = 0; dm < 2; ++dm)
#pragma unroll
            for (int nf = 0; nf < 4; ++nf)
              acc[q * 2 + dm][nf] = __builtin_amdgcn_mfma_f32_16x16x32_bf16(
                  Af[ks][dm], Bf[ks][nf], acc[q * 2 + dm][nf], 0, 0, 0);
        __builtin_amdgcn_s_setprio(0);
        if (q == 3) {
          if (half == 0) {
            if (s2) asm volatile("s_waitcnt vmcnt(6)" ::: "memory");
            else    asm volatile("s_waitcnt vmcnt(0)" ::: "memory");
          } else if (s2) {
            if (s3) asm volatile("s_waitcnt vmcnt(6)" ::: "memory");
            else    asm volatile("s_waitcnt vmcnt(0)" ::: "memory");
          }
        }
        __builtin_amdgcn_sched_barrier(0);
        __builtin_amdgcn_s_barrier();
      }
    }
  }

  int r0 = (l >> 4) * 4;
#pragma unroll
  for (int mf = 0; mf < 8; ++mf) {
    int gr = mb + ((mf >> 2) << 7) + wr * 64 + (mf & 3) * 16 + r0;
#pragma unroll
    for (int nf = 0; nf < 4; ++nf) {
      int gc = nb + wc * 64 + nf * 16 + lr;
      float bv = bias[gc];
#pragma unroll
      for (int rr = 0; rr < 4; ++rr) {
        float v = acc[mf][nf][rr] + bv;
        size_t o = (size_t)(gr + rr) * N + gc;
        if constexpr (EPI == 1) {
          outb[o] = f2bf(v);
        } else {
          float g = 0.5f * v * (1.0f + erff(v * 0.70710678f));
          outb[o] = f2bf(g);
        }
      }
    }
  }
}

// ---------------- 256x192 8-wave 8-PHASE pipelined GEMM (QKV: full 256-block fill) ----------
template <int EPI>
__global__ __launch_bounds__(512, 1) void k_gemm5(const u16* __restrict__ A,
                                                  const u16* __restrict__ Wt,
                                                  const float* __restrict__ bias,
                                                  u16* __restrict__ outb,
                                                  int N, int K, int gridN) {
  __shared__ char lds[2][57344];
  int t = threadIdx.x, l = t & 63, wid = t >> 6;
  int wr = wid >> 2, wc = wid & 3;        // wave tile 128(M) x 48(N)
  int lr = l & 15, lk16 = (l >> 4) * 16;

  int nwg = gridDim.x, wg = blockIdx.x;
  int qq = nwg >> 3, r8 = nwg & 7;
  int xcd = wg & 7, loc = wg >> 3;
  int swz = (xcd < r8 ? xcd * (qq + 1) : r8 * (qq + 1) + (xcd - r8) * qq) + loc;
  int mblk = swz / gridN, nblk = swz - mblk * gridN;
  int mb = mblk * 256, nb = nblk * 192;
  int NT = K >> 6;
  const u16* Ab = A  + (size_t)mb * K;
  const u16* Bb = Wt + (size_t)nb * K;

  int srow = t >> 3, skb = (t & 7) * 16;

  auto stageA = [&](int kt, int ht) {
    int b = kt & 1;
    char* dst = &lds[b][ht * 16384];
    const u16* s0 = Ab + ((size_t)(ht << 7)) * K + kt * 64;
#pragma unroll
    for (int j = 0; j < 2; ++j) {
      int row = j * 64 + srow;
      int kb = skb ^ ((row & 7) << 4);
      gload16(s0 + (size_t)row * K + (kb >> 1), dst + j * 8192 + t * 16);
    }
  };
  auto stageB = [&](int kt, int bt) {
    int b = kt & 1;
    char* dst = &lds[b][32768 + bt * 8192];
    int row = bt * 64 + srow;
    int kb = skb ^ ((row & 7) << 4);
    gload16(Bb + (size_t)row * K + kt * 64 + (kb >> 1), dst + t * 16);
  };

  f32x4 acc[8][3] = {};

  stageA(0, 0); stageA(0, 1); stageB(0, 0); stageB(0, 1); stageB(0, 2);
  stageB(1, 0); stageB(1, 1); stageB(1, 2); stageA(1, 0);
  asm volatile("s_waitcnt vmcnt(5)" ::: "memory");
  __builtin_amdgcn_s_barrier();
  __builtin_amdgcn_sched_barrier(0);

  for (int kt = 0; kt < NT; kt += 2) {
    bool s2 = (kt + 2) < NT, s3 = (kt + 3) < NT;
#pragma unroll
    for (int half = 0; half < 2; ++half) {
      int buf = half;
      bf16x8 Bf[2][3];
#pragma unroll
      for (int q = 0; q < 4; ++q) {
        bf16x8 Af[2][2];
        if (q == 0) {
#pragma unroll
          for (int ks = 0; ks < 2; ++ks)
#pragma unroll
            for (int nf = 0; nf < 3; ++nf) {
              int grow = wc * 48 + nf * 16 + lr;
              int rr = grow & 63;
              int kb = (ks * 64 + lk16) ^ ((rr & 7) << 4);
              Bf[ks][nf] = *(const bf16x8*)(&lds[buf][32768 + (grow >> 6) * 8192] + rr * 128 + kb);
            }
        }
#pragma unroll
        for (int ks = 0; ks < 2; ++ks)
#pragma unroll
          for (int dm = 0; dm < 2; ++dm) {
            int mf = q * 2 + dm;
            int grow = wr * 64 + (mf & 3) * 16 + lr;
            int kb = (ks * 64 + lk16) ^ ((grow & 7) << 4);
            Af[ks][dm] = *(const bf16x8*)(&lds[buf][(mf >> 2) * 16384] + grow * 128 + kb);
          }
        if (half == 0) {
          if (q == 0)      stageA(kt + 1, 1);
          else if (q == 1) { if (s2) stageB(kt + 2, 0); }
          else if (q == 2) { if (s2) { stageB(kt + 2, 1); stageA(kt + 2, 0); } }
          else             { if (s2) stageB(kt + 2, 2); }
        } else {
          if (q == 0)      { if (s2) stageA(kt + 2, 1); }
          else if (q == 1) { if (s3) stageB(kt + 3, 0); }
          else if (q == 2) { if (s3) { stageB(kt + 3, 1); stageA(kt + 3, 0); } }
          else             { if (s3) stageB(kt + 3, 2); }
        }
        __builtin_amdgcn_sched_barrier(0);
        __builtin_amdgcn_s_barrier();
        asm volatile("s_waitcnt lgkmcnt(0)" ::: "memory");
        __builtin_amdgcn_sched_barrier(0);
        __builtin_amdgcn_s_setprio(1);
#pragma unroll
        for (int ks = 0; ks < 2; ++ks)
#pragma unroll
          for (int dm = 0; dm < 2; ++dm)
#pragma unroll
            for (int nf = 0; nf < 3; ++nf)
              acc[q * 2 + dm][nf] = __builtin_amdgcn_mfma_f32_16x16x32_bf16(
                  Af[ks][dm], Bf[ks][nf], acc[q * 2 + dm][nf], 0, 0, 0);
        __builtin_amdgcn_s_setprio(0);
        if (q == 3) {
          if (half == 0) {
            if (s2) asm volatile("s_waitcnt vmcnt(5)" ::: "memory");
            else    asm volatile("s_waitcnt vmcnt(0)" ::: "memory");
          } else if (s2) {
            if (s3) asm volatile("s_waitcnt vmcnt(5)" ::: "memory");
            else    asm volatile("s_waitcnt vmcnt(0)" ::: "memory");
          }
        }
        __builtin_amdgcn_sched_barrier(0);
        __builtin_amdgcn_s_barrier();
      }
    }
  }

  int r0 = (l >> 4) * 4;
#pragma unroll
  for (int mf = 0; mf < 8; ++mf) {
    int gr = mb + ((mf >> 2) << 7) + wr * 64 + (mf & 3) * 16 + r0;
#pragma unroll
    for (int nf = 0; nf < 3; ++nf) {
      int gc = nb + wc * 48 + nf * 16 + lr;
      float bv = bias[gc];
#pragma unroll
      for (int rr = 0; rr < 4; ++rr) {
        float v = acc[mf][nf][rr] + bv;
        size_t o = (size_t)(gr + rr) * N + gc;
        outb[o] = f2bf(v);
      }
    }
  }
}

// ---------------- 128x128 4-wave pipelined GEMM ----------------
// EPI: 0 = f32 resid-add store ; 3 = f32 row-guarded, no bias
template <int EPI>
__global__ __launch_bounds__(256, 2) void k_gemm3(const u16* __restrict__ A,
                                                  const u16* __restrict__ Wt,
                                                  const float* __restrict__ bias,
                                                  float* __restrict__ outf,
                                                  const float* __restrict__ resid,
                                                  int N, int K, int gridN, int Mv) {
  constexpr int BTILE = 16384;
  __shared__ u16 lds[2][128 * 64 * 2];

  int t = threadIdx.x, l = t & 63, wid = t >> 6;
  int wr = wid >> 1, wc = wid & 1;
  int lr = l & 15, lk16 = (l >> 4) * 16;

  int nwg = gridDim.x, wg = blockIdx.x;
  int q = nwg >> 3, r = nwg & 7;
  int xcd = wg & 7, loc = wg >> 3;
  int swz = (xcd < r ? xcd * (q + 1) : r * (q + 1) + (xcd - r) * q) + loc;
  int mblk = swz / gridN;
  int nblk = swz - mblk * gridN;
  int mb = mblk * 128, nb = nblk * 128;
  int NT = K >> 6;
  const u16* Ab = A  + (size_t)mb * K;
  const u16* Bb = Wt + (size_t)nb * K;

  int srow = t >> 3;
  int skb  = (t & 7) * 16;

  auto stage = [&](int kt, int b) {
    const u16* As = Ab + kt * 64;
    char* LD = (char*)&lds[b][0];
#pragma unroll
    for (int j = 0; j < 4; ++j) {
      int row = j * 32 + srow;
      int kb  = skb ^ ((row & 7) << 4);
      gload16(As + (size_t)row * K + (kb >> 1), LD + j * 4096 + t * 16);
    }
    const u16* Bs = Bb + kt * 64;
#pragma unroll
    for (int j = 0; j < 4; ++j) {
      int row = j * 32 + srow;
      int kb  = skb ^ ((row & 7) << 4);
      gload16(Bs + (size_t)row * K + (kb >> 1), LD + BTILE + j * 4096 + t * 16);
    }
  };

  f32x4 acc[4][4] = {};

  auto tile = [&](int b) {
    const char* LA = (const char*)&lds[b][0];
    const char* LB = LA + BTILE;
    bf16x8 bfr[2][4], afr[2][4];
#pragma unroll
    for (int ks = 0; ks < 2; ++ks)
#pragma unroll
      for (int n = 0; n < 4; ++n) {
        int rr = wc * 64 + n * 16 + lr;
        int kb = (ks * 64 + lk16) ^ ((rr & 7) << 4);
        bfr[ks][n] = *(const bf16x8*)(LB + rr * 128 + kb);
      }
#pragma unroll
    for (int ks = 0; ks < 2; ++ks)
#pragma unroll
      for (int m = 0; m < 4; ++m) {
        int rr = wr * 64 + m * 16 + lr;
        int kb = (ks * 64 + lk16) ^ ((rr & 7) << 4);
        afr[ks][m] = *(const bf16x8*)(LA + rr * 128 + kb);
      }
    __builtin_amdgcn_s_setprio(1);
#pragma unroll
    for (int ks = 0; ks < 2; ++ks)
#pragma unroll
      for (int m = 0; m < 4; ++m)
#pragma unroll
        for (int n = 0; n < 4; ++n)
          acc[m][n] = __builtin_amdgcn_mfma_f32_16x16x32_bf16(
              afr[ks][m], bfr[ks][n], acc[m][n], 0, 0, 0);
    __builtin_amdgcn_s_setprio(0);
  };

  stage(0, 0);
  stage(1, 1);
  asm volatile("s_waitcnt vmcnt(8)" ::: "memory");
  __builtin_amdgcn_s_barrier();
  __builtin_amdgcn_sched_barrier(0);

  for (int kt = 0; kt < NT; kt += 2) {
#pragma unroll
    for (int sub = 0; sub < 2; ++sub) {
      tile(sub);
      asm volatile("s_waitcnt lgkmcnt(0)" ::: "memory");
      __builtin_amdgcn_s_barrier();
      __builtin_amdgcn_sched_barrier(0);
      if (kt + 2 + sub < NT) {
        stage(kt + 2 + sub, sub);
        asm volatile("s_waitcnt vmcnt(8)" ::: "memory");
      } else {
        asm volatile("s_waitcnt vmcnt(0)" ::: "memory");
      }
      __builtin_amdgcn_s_barrier();
      __builtin_amdgcn_sched_barrier(0);
    }
  }

  int r0 = (l >> 4) * 4;
#pragma unroll
  for (int m = 0; m < 4; ++m) {
    int gr = mb + wr * 64 + m * 16 + r0;
#pragma unroll
    for (int n = 0; n < 4; ++n) {
      int gc = nb + wc * 64 + n * 16 + lr;
      float bv = 0.f;
      if constexpr (EPI == 0) bv = bias[gc];
#pragma unroll
      for (int rr = 0; rr < 4; ++rr) {
        int grr = gr + rr;
        float v = acc[m][n][rr] + bv;
        size_t o = (size_t)grr * N + gc;
        if constexpr (EPI == 0) {
          outf[o] = v + resid[o];
        } else {
          if (grr < Mv) outf[o] = v;
        }
      }
    }
  }
}

// ---------------- MLP2 split-K=2: 128x128 tiles, f32 partial slices ----------------
__global__ __launch_bounds__(256, 2) void k_gemm3p(const u16* __restrict__ A,
                                                   const u16* __restrict__ Wt,
                                                   float* __restrict__ pbuf,
                                                   int N, int K, int gridN) {
  constexpr int KS = 2;
  constexpr int BTILE = 16384;
  __shared__ u16 lds[2][128 * 64 * 2];

  int t = threadIdx.x, l = t & 63, wid = t >> 6;
  int wr = wid >> 1, wc = wid & 1;
  int lr = l & 15, lk16 = (l >> 4) * 16;

  int nwg = gridDim.x, wg = blockIdx.x;
  int q = nwg >> 3, r = nwg & 7;
  int xcd = wg & 7, loc = wg >> 3;
  int swz = (xcd < r ? xcd * (q + 1) : r * (q + 1) + (xcd - r) * q) + loc;
  int mblk = swz / (gridN * KS);
  int rest = swz - mblk * (gridN * KS);
  int nblk = rest / KS;
  int kz   = rest - nblk * KS;
  int mb = mblk * 128, nb = nblk * 128;
  int Ksub = K / KS;
  int NT = Ksub >> 6;
  const u16* Ab = A  + (size_t)mb * K + (size_t)kz * Ksub;
  const u16* Bb = Wt + (size_t)nb * K + (size_t)kz * Ksub;

  int srow = t >> 3;
  int skb  = (t & 7) * 16;

  auto stage = [&](int kt, int b) {
    const u16* As = Ab + kt * 64;
    char* LD = (char*)&lds[b][0];
#pragma unroll
    for (int j = 0; j < 4; ++j) {
      int row = j * 32 + srow;
      int kb  = skb ^ ((row & 7) << 4);
      gload16(As + (size_t)row * K + (kb >> 1), LD + j * 4096 + t * 16);
    }
    const u16* Bs = Bb + kt * 64;
#pragma unroll
    for (int j = 0; j < 4; ++j) {
      int row = j * 32 + srow;
      int kb  = skb ^ ((row & 7) << 4);
      gload16(Bs + (size_t)row * K + (kb >> 1), LD + BTILE + j * 4096 + t * 16);
    }
  };

  f32x4 acc[4][4] = {};

  auto tile = [&](int b) {
    const char* LA = (const char*)&lds[b][0];
    const char* LB = LA + BTILE;
    bf16x8 bfr[2][4], afr[2][4];
#pragma unroll
    for (int ks = 0; ks < 2; ++ks)
#pragma unroll
      for (int n = 0; n < 4; ++n) {
        int rr = wc * 64 + n * 16 + lr;
        int kb = (ks * 64 + lk16) ^ ((rr & 7) << 4);
        bfr[ks][n] = *(const bf16x8*)(LB + rr * 128 + kb);
      }
#pragma unroll
    for (int ks = 0; ks < 2; ++ks)
#pragma unroll
      for (int m = 0; m < 4; ++m) {
        int rr = wr * 64 + m * 16 + lr;
        int kb = (ks * 64 + lk16) ^ ((rr & 7) << 4);
        afr[ks][m] = *(const bf16x8*)(LA + rr * 128 + kb);
      }
    __builtin_amdgcn_s_setprio(1);
#pragma unroll
    for (int ks = 0; ks < 2; ++ks)
#pragma unroll
      for (int m = 0; m < 4; ++m)
#pragma unroll
        for (int n = 0; n < 4; ++n)
          acc[m][n] = __builtin_amdgcn_mfma_f32_16x16x32_bf16(
              afr[ks][m], bfr[ks][n], acc[m][n], 0, 0, 0);
    __builtin_amdgcn_s_setprio(0);
  };

  stage(0, 0);
  stage(1, 1);
  asm volatile("s_waitcnt vmcnt(8)" ::: "memory");
  __builtin_amdgcn_s_barrier();
  __builtin_amdgcn_sched_barrier(0);

  for (int kt = 0; kt < NT; kt += 2) {
#pragma unroll
    for (int sub = 0; sub < 2; ++sub) {
      tile(sub);
      asm volatile("s_waitcnt lgkmcnt(0)" ::: "memory");
      __builtin_amdgcn_s_barrier();
      __builtin_amdgcn_sched_barrier(0);
      if (kt + 2 + sub < NT) {
        stage(kt + 2 + sub, sub);
        asm volatile("s_waitcnt vmcnt(8)" ::: "memory");
      } else {
        asm volatile("s_waitcnt vmcnt(0)" ::: "memory");
      }
      __builtin_amdgcn_s_barrier();
      __builtin_amdgcn_sched_barrier(0);
    }
  }

  float* pb = pbuf + (size_t)kz * PB2;
  int r0 = (l >> 4) * 4;
#pragma unroll
  for (int m = 0; m < 4; ++m) {
    int gr = mb + wr * 64 + m * 16 + r0;
#pragma unroll
    for (int n = 0; n < 4; ++n) {
      int gc = nb + wc * 64 + n * 16 + lr;
#pragma unroll
      for (int rr = 0; rr < 4; ++rr)
        pb[(size_t)(gr + rr) * N + gc] = acc[m][n][rr];
    }
  }
}

// ---------------- head GEMM split-K=8: 128x128 tiles, f32 partial slices ----------------
__global__ __launch_bounds__(256, 2) void k_gemm3sk(const u16* __restrict__ A,
                                                    const u16* __restrict__ Wt,
                                                    float* __restrict__ pbuf,
                                                    int N, int K) {
  constexpr int KS = 8;
  constexpr int BTILE = 16384;
  __shared__ u16 lds[2][128 * 64 * 2];

  int t = threadIdx.x, l = t & 63, wid = t >> 6;
  int wr = wid >> 1, wc = wid & 1;
  int lr = l & 15, lk16 = (l >> 4) * 16;

  int nwg = gridDim.x, wg = blockIdx.x;
  int q = nwg >> 3, r = nwg & 7;
  int xcd = wg & 7, loc = wg >> 3;
  int swz = (xcd < r ? xcd * (q + 1) : r * (q + 1) + (xcd - r) * q) + loc;
  int mblk = swz / KS;
  int kz   = swz - mblk * KS;
  int mb = mblk * 128, nb = 0;
  int Ksub = K / KS;
  int NT = Ksub >> 6;               // = 2
  const u16* Ab = A  + (size_t)mb * K + (size_t)kz * Ksub;
  const u16* Bb = Wt + (size_t)kz * Ksub;

  int srow = t >> 3;
  int skb  = (t & 7) * 16;

  auto stage = [&](int kt, int b) {
    const u16* As = Ab + kt * 64;
    char* LD = (char*)&lds[b][0];
#pragma unroll
    for (int j = 0; j < 4; ++j) {
      int row = j * 32 + srow;
      int kb  = skb ^ ((row & 7) << 4);
      gload16(As + (size_t)row * K + (kb >> 1), LD + j * 4096 + t * 16);
    }
    const u16* Bs = Bb + kt * 64;
#pragma unroll
    for (int j = 0; j < 4; ++j) {
      int row = j * 32 + srow;
      int kb  = skb ^ ((row & 7) << 4);
      gload16(Bs + (size_t)row * K + (kb >> 1), LD + BTILE + j * 4096 + t * 16);
    }
  };

  f32x4 acc[4][4] = {};

  auto tile = [&](int b) {
    const char* LA = (const char*)&lds[b][0];
    const char* LB = LA + BTILE;
    bf16x8 bfr[2][4], afr[2][4];
#pragma unroll
    for (int ks = 0; ks < 2; ++ks)
#pragma unroll
      for (int n = 0; n < 4; ++n) {
        int rr = wc * 64 + n * 16 + lr;
        int kb = (ks * 64 + lk16) ^ ((rr & 7) << 4);
        bfr[ks][n] = *(const bf16x8*)(LB + rr * 128 + kb);
      }
#pragma unroll
    for (int ks = 0; ks < 2; ++ks)
#pragma unroll
      for (int m = 0; m < 4; ++m) {
        int rr = wr * 64 + m * 16 + lr;
        int kb = (ks * 64 + lk16) ^ ((rr & 7) << 4);
        afr[ks][m] = *(const bf16x8*)(LA + rr * 128 + kb);
      }
#pragma unroll
    for (int ks = 0; ks < 2; ++ks)
#pragma unroll
      for (int m = 0; m < 4; ++m)
#pragma unroll
        for (int n = 0; n < 4; ++n)
          acc[m][n] = __builtin_amdgcn_mfma_f32_16x16x32_bf16(
              afr[ks][m], bfr[ks][n], acc[m][n], 0, 0, 0);
  };

  stage(0, 0);
  stage(1, 1);
  asm volatile("s_waitcnt vmcnt(8)" ::: "memory");
  __builtin_amdgcn_s_barrier();
  __builtin_amdgcn_sched_barrier(0);

  for (int kt = 0; kt < NT; kt += 2) {
#pragma unroll
    for (int sub = 0; sub < 2; ++sub) {
      tile(sub);
      asm volatile("s_waitcnt lgkmcnt(0)" ::: "memory");
      __builtin_amdgcn_s_barrier();
      __builtin_amdgcn_sched_barrier(0);
      if (kt + 2 + sub < NT) {
        stage(kt + 2 + sub, sub);
        asm volatile("s_waitcnt vmcnt(8)" ::: "memory");
      } else {
        asm volatile("s_waitcnt vmcnt(0)" ::: "memory");
      }
      __builtin_amdgcn_s_barrier();
      __builtin_amdgcn_sched_barrier(0);
    }
  }

  float* pb = pbuf + (size_t)kz * PH;
  int r0 = (l >> 4) * 4;
#pragma unroll
  for (int m = 0; m < 4; ++m) {
    int gr = mb + wr * 64 + m * 16 + r0;
#pragma unroll
    for (int n = 0; n < 4; ++n) {
      int gc = nb + wc * 64 + n * 16 + lr;
#pragma unroll
      for (int rr = 0; rr < 4; ++rr)
        pb[(size_t)(gr + rr) * N + gc] = acc[m][n][rr];
    }
  }
}

// head reduce: out[i] = sum over 8 slices (exact-fit grid: MV*VV threads)
__global__ __launch_bounds__(256) void k_redhead(const float* __restrict__ pb,
                                                 float* __restrict__ out) {
  int i = blockIdx.x * 256 + threadIdx.x;
  float s = 0.f;
#pragma unroll
  for (int z = 0; z < 8; ++z) s += pb[(size_t)z * PH + i];
  out[i] = s;
}

// ---------------- V transpose: qkv[., 2048+h*64+d] -> vt[b,h,d,t] ----------------
__global__ __launch_bounds__(256) void k_vtrans(const u16* __restrict__ qkv,
                                                u16* __restrict__ vt) {
  __shared__ u16 tile[64][66];
  int bh = blockIdx.y;
  int b = bh >> 4, h = bh & 15;
  int t0 = blockIdx.x * 64;
  int t = threadIdx.x;
  int r = t >> 4, c4 = (t & 15) * 4;
#pragma unroll
  for (int i = 0; i < 4; ++i) {
    int tt = r + i * 16;
    int trow = t0 + tt;
    int srow = b * TT + (trow < TT ? trow : TT - 1);
    ushort4 v = *(const ushort4*)(qkv + (size_t)srow * 3072 + 2048 + h * 64 + c4);
    tile[tt][c4 + 0] = v.x; tile[tt][c4 + 1] = v.y;
    tile[tt][c4 + 2] = v.z; tile[tt][c4 + 3] = v.w;
  }
  __syncthreads();
#pragma unroll
  for (int i = 0; i < 4; ++i) {
    int d = r + i * 16;
    ushort4 o;
    o.x = (t0 + c4 + 0 < TT) ? tile[c4 + 0][d] : (u16)0;
    o.y = (t0 + c4 + 1 < TT) ? tile[c4 + 1][d] : (u16)0;
    o.z = (t0 + c4 + 2 < TT) ? tile[c4 + 2][d] : (u16)0;
    o.w = (t0 + c4 + 3 < TT) ? tile[c4 + 3][d] : (u16)0;
    *(ushort4*)(vt + ((size_t)bh * 64 + d) * TP + t0 + c4) = o;
  }
}

// ---------------- flash attention: block = (b,h, 128 q rows), 8 waves ----------------
__global__ __launch_bounds__(512, 2) void k_attn2(const u16* __restrict__ qkv,
                                                  const u16* __restrict__ vt,
                                                  u16* __restrict__ y) {
  __shared__ u16 Kb[2][64 * 64];
  __shared__ u16 Vb[2][64 * 64];
  __shared__ u16 Pb[8][16 * 64];
  int t = threadIdx.x, l = t & 63, w = t >> 6;

  int nwg = gridDim.x, wg = blockIdx.x;
  int swz = (wg & 7) * (nwg >> 3) + (wg >> 3);
  int bh = swz >> 2, qt = swz & 3;
  int b = bh >> 4, h = bh & 15;
  int q0 = qt * 128;
  int lr = l & 15, lg = l >> 4, lk8 = lg * 8;

  const float ISC = 0.125f;

  bf16x8 Qa[2];
  {
    int qs = q0 + w * 16 + lr;
    const u16* qp = qkv + (size_t)(b * TT + (qs < TT ? qs : TT - 1)) * 3072 + h * 64;
    Qa[0] = *(const bf16x8*)(qp + lk8);
    Qa[1] = *(const bf16x8*)(qp + 32 + lk8);
  }

  int NT = (q0 + 128) >> 6;

  int srow = w * 8 + (l >> 3);
  int sb16 = (l & 7) * 16;
  int bcol = sb16 ^ ((srow & 7) << 4);
  const u16* Ksrc = qkv + 1024 + h * 64;
  const char* Vsrc = (const char*)(vt + ((size_t)bh * 64 + srow) * TP);

  auto stage = [&](int kt, int buf) {
    int kv0 = kt * 64;
    int kvr = kv0 + srow;
    int krow = b * TT + (kvr < TT ? kvr : TT - 1);
    gload16((const char*)(Ksrc + (size_t)krow * 3072) + bcol, (char*)&Kb[buf][0] + t * 16);
    gload16(Vsrc + kv0 * 2 + bcol, (char*)&Vb[buf][0] + t * 16);
  };

  f32x4 O[4] = {};
  float m_[4], s_[4];
#pragma unroll
  for (int r = 0; r < 4; ++r) { m_[r] = -1e30f; s_[r] = 0.f; }

  stage(0, 0);
  for (int kt = 0; kt < NT; ++kt) {
    int buf = kt & 1;
    if (kt + 1 < NT) {
      stage(kt + 1, buf ^ 1);
      asm volatile("s_waitcnt vmcnt(2)" ::: "memory");
    } else {
      asm volatile("s_waitcnt vmcnt(0)" ::: "memory");
    }
    __builtin_amdgcn_s_barrier();

    int kv0 = kt * 64;
    f32x4 S[4];
    const char* LK = (const char*)&Kb[buf][0];
#pragma unroll
    for (int j = 0; j < 4; ++j) {
      f32x4 a = {};
#pragma unroll
      for (int ks = 0; ks < 2; ++ks) {
        int row = j * 16 + lr;
        int kb = ((ks * 32 + lk8) * 2) ^ ((row & 7) << 4);
        bf16x8 kf = *(const bf16x8*)(LK + row * 128 + kb);
        a = __builtin_amdgcn_mfma_f32_16x16x32_bf16(Qa[ks], kf, a, 0, 0, 0);
      }
      S[j] = a;
    }
    int qbase = q0 + w * 16 + lg * 4;
#pragma unroll
    for (int j = 0; j < 4; ++j) {
      int kv = kv0 + j * 16 + lr;
#pragma unroll
      for (int r = 0; r < 4; ++r) {
        bool valid = (kv <= qbase + r) && (kv < TT);
        S[j][r] = valid ? S[j][r] : -1e30f;
      }
    }
    float mx[4];
#pragma unroll
    for (int r = 0; r < 4; ++r)
      mx[r] = fmaxf(fmaxf(S[0][r], S[1][r]), fmaxf(S[2][r], S[3][r]));
#pragma unroll
    for (int r = 0; r < 4; ++r) {
      mx[r] = fmaxf(mx[r], __shfl_xor(mx[r], 1));
      mx[r] = fmaxf(mx[r], __shfl_xor(mx[r], 2));
      mx[r] = fmaxf(mx[r], __shfl_xor(mx[r], 4));
      mx[r] = fmaxf(mx[r], __shfl_xor(mx[r], 8));
    }
    float sc[4];
#pragma unroll
    for (int r = 0; r < 4; ++r) {
      float mn = fmaxf(m_[r], mx[r]);
      sc[r] = __expf((m_[r] - mn) * ISC);
      m_[r] = mn;
      s_[r] *= sc[r];
    }
#pragma unroll
    for (int j = 0; j < 4; ++j)
#pragma unroll
      for (int r = 0; r < 4; ++r) O[j][r] *= sc[r];
    float rs[4] = {0.f, 0.f, 0.f, 0.f};
    char* LP = (char*)&Pb[w][0];
#pragma unroll
    for (int j = 0; j < 4; ++j) {
#pragma unroll
      for (int r = 0; r < 4; ++r) {
        float p = __expf((S[j][r] - m_[r]) * ISC);
        rs[r] += p;
        int row = lg * 4 + r;
        int addr = (row * 128 + (j * 16 + lr) * 2) ^ ((row & 7) << 4);
        *(u16*)(LP + addr) = f2bf(p);
      }
    }
#pragma unroll
    for (int r = 0; r < 4; ++r) {
      rs[r] += __shfl_xor(rs[r], 1);
      rs[r] += __shfl_xor(rs[r], 2);
      rs[r] += __shfl_xor(rs[r], 4);
      rs[r] += __shfl_xor(rs[r], 8);
      s_[r] += rs[r];
    }
    bf16x8 Pa[2];
#pragma unroll
    for (int ks = 0; ks < 2; ++ks) {
      int addr = (lr * 128 + (ks * 32 + lk8) * 2) ^ ((lr & 7) << 4);
      Pa[ks] = *(const bf16x8*)(LP + addr);
    }
    const char* LV = (const char*)&Vb[buf][0];
#pragma unroll
    for (int j = 0; j < 4; ++j) {
#pragma unroll
      for (int ks = 0; ks < 2; ++ks) {
        int row = j * 16 + lr;
        int kb = ((ks * 32 + lk8) * 2) ^ ((row & 7) << 4);
        bf16x8 vf = *(const bf16x8*)(LV + row * 128 + kb);
        O[j] = __builtin_amdgcn_mfma_f32_16x16x32_bf16(Pa[ks], vf, O[j], 0, 0, 0);
      }
    }
    asm volatile("s_waitcnt lgkmcnt(0)" ::: "memory");
    __builtin_amdgcn_s_barrier();
  }

  int qs0 = q0 + w * 16 + lg * 4;
#pragma unroll
  for (int r = 0; r < 4; ++r) {
    float inv = 1.0f / s_[r];
    int qs = qs0 + r;
    if (qs < TT) {
      u16* yp = y + (size_t)(b * TT + qs) * CC + h * 64;
#pragma unroll
      for (int j = 0; j < 4; ++j)
        yp[j * 16 + lr] = f2bf(O[j][r] * inv);
    }
  }
}

// ---------------- host ----------------
extern "C" void kernel_launch(void* const* d_in, const int* in_sizes, int n_in,
                              void* d_out, int out_size, void* d_ws, size_t ws_size,
                              hipStream_t stream) {
  (void)in_sizes; (void)n_in; (void)out_size;
  const int*   idx  = (const int*)  d_in[0];
  const float* tok  = (const float*)d_in[1];
  const float* pos  = (const float*)d_in[2];
  const float* ln1w = (const float*)d_in[3];
  const float* ln1b = (const float*)d_in[4];
  const float* Wq   = (const float*)d_in[5];
  const float* bq   = (const float*)d_in[6];
  const float* Wk   = (const float*)d_in[7];
  const float* bk   = (const float*)d_in[8];
  const float* Wv   = (const float*)d_in[9];
  const float* bv   = (const float*)d_in[10];
  const float* Wp   = (const float*)d_in[11];
  const float* bp   = (const float*)d_in[12];
  const float* ln2w = (const float*)d_in[13];
  const float* ln2b = (const float*)d_in[14];
  const float* W1   = (const float*)d_in[15];
  const float* b1   = (const float*)d_in[16];
  const float* W2   = (const float*)d_in[17];
  const float* b2   = (const float*)d_in[18];
  const float* lnfw = (const float*)d_in[19];
  const float* lnfb = (const float*)d_in[20];
  const float* headw= (const float*)d_in[21];
  float* out = (float*)d_out;

  char* p = (char*)d_ws;
  auto alloc = [&](size_t bytes) { char* r = p; p += (bytes + 255) & ~(size_t)255; return r; };
  u16*   wqkv_t = (u16*)  alloc((size_t)LL * 3 * CC * CC * 2);
  u16*   wp_t   = (u16*)  alloc((size_t)LL * CC * CC * 2);
  u16*   w1_t   = (u16*)  alloc((size_t)LL * FF_ * CC * 2);
  u16*   w2_t   = (u16*)  alloc((size_t)LL * CC * FF_ * 2);
  u16*   headb  = (u16*)  alloc((size_t)VV * CC * 2);
  float* bqkv   = (float*)alloc((size_t)LL * 3 * CC * 4);
  float* x      = (float*)alloc((size_t)MP * CC * 4);
  u16*   hbuf   = (u16*)  alloc((size_t)MP * CC * 2);
  u16*   qkv    = (u16*)  alloc((size_t)MP * 3 * CC * 2);
  u16*   vt     = (u16*)  alloc((size_t)NB * HH * 64 * TP * 2);
  u16*   ybuf   = (u16*)  alloc((size_t)MP * CC * 2);
  u16*   ffb    = (u16*)  alloc((size_t)MP * FF_ * 2);
  float* pbuf   = (float*)alloc((size_t)8 * PH * 4);    // 16 MB head split-K partials
  float* pbuf2  = (float*)alloc((size_t)2 * PB2 * 4);   // 32 MB mlp2 split-K partials
  bool havePB = ((size_t)(p - (char*)d_ws) <= ws_size);

  // mega prologue: embed + all weight transposes + head cast + bias pack
  int prepBlocks = MP + 3 * 8192 + (VV * CC + LL * 3 * CC + 255) / 256;
  k_prep_all<<<prepBlocks, 256, 0, stream>>>(idx, tok, pos, x, Wq, Wk, Wv, Wp, W1, W2,
                                             headw, bq, bk, bv,
                                             wqkv_t, wp_t, w1_t, w2_t, headb, bqkv);
  k_ln<<<MP / 4, 256, 0, stream>>>(x, ln1w, ln1b, hbuf);       // layer 0 ln1

  for (int l = 0; l < LL; ++l) {
    const float* nw = (l < LL - 1) ? ln1w + (size_t)(l + 1) * CC : lnfw;
    const float* nb = (l < LL - 1) ? ln1b + (size_t)(l + 1) * CC : lnfb;
    // QKV: M=4096, N=3072, K=1024  (256x192 8-phase, 256 blocks = full fill)
    k_gemm5<1><<<16 * 16, 512, 0, stream>>>(hbuf, wqkv_t + (size_t)l * 3 * CC * CC,
                                            bqkv + (size_t)l * 3 * CC, qkv, 3 * CC, CC, 16);
    k_vtrans<<<dim3(8, NB * HH), 256, 0, stream>>>(qkv, vt);
    k_attn2<<<NB * HH * 4, 512, 0, stream>>>(qkv, vt, ybuf);
    // proj: M=4096, N=1024, K=1024  (128x128, resid-add into x)
    k_gemm3<0><<<32 * 8, 256, 0, stream>>>(ybuf, wp_t + (size_t)l * CC * CC,
                                           bp + (size_t)l * CC, x, x, CC, CC, 8, MP);
    k_ln<<<MP / 4, 256, 0, stream>>>(x, ln2w + (size_t)l * CC, ln2b + (size_t)l * CC, hbuf);
    // MLP1: M=4096, N=4096, K=1024, GELU  (256x256 8-phase)
    k_gemm4<2><<<16 * 16, 512, 0, stream>>>(hbuf, w1_t + (size_t)l * FF_ * CC,
                                            b1 + (size_t)l * FF_, ffb, FF_, CC, 16);
    if (havePB) {
      // MLP2: M=4096, N=1024, K=4096  split-K=2 (128x128, 512 blocks, 2/CU), f32 partials
      k_gemm3p<<<32 * 8 * 2, 256, 0, stream>>>(ffb, w2_t + (size_t)l * CC * FF_, pbuf2, CC, FF_, 8);
      // fused: x += p0+p1+b2 ; hbuf = LN_next(x)
      k_redln2<<<MP / 4, 256, 0, stream>>>(x, pbuf2, b2 + (size_t)l * CC, nw, nb, hbuf);
    } else {
      k_gemm3<0><<<32 * 8, 256, 0, stream>>>(ffb, w2_t + (size_t)l * CC * FF_,
                                             b2 + (size_t)l * CC, x, x, CC, FF_, 8, MP);
      k_ln<<<MP / 4, 256, 0, stream>>>(x, nw, nb, hbuf);
    }
  }

  if (havePB) {
    // head: split-K=8, 256 blocks full fill, then reduce
    k_gemm3sk<<<32 * 8, 256, 0, stream>>>(hbuf, headb, pbuf, VV, CC);
    k_redhead<<<(MV * VV) / 256, 256, 0, stream>>>(pbuf, out);
  } else {
    k_gemm3<3><<<32 * 1, 256, 0, stream>>>(hbuf, headb, nullptr, out, nullptr, VV, CC, 1, MV);
  }
}